// Round 9
// baseline (467.990 us; speedup 1.0000x reference)
//
#include <hip/hip_runtime.h>
#include <cstdint>
#include <math.h>

typedef _Float16 half_t;
typedef __attribute__((ext_vector_type(8))) _Float16 half8;
typedef __attribute__((ext_vector_type(4))) float floatx4;

// ---------------- workspace byte layout ----------------
// bbwh   @ 0            12,582,912   fp16 [32 nt][96 s][4 kg][64 n][16B]
// zpad   @ 12,582,912   1,024
// topidx @ 12,583,936   1,024
// scores @ 12,584,960   103,424
// y1     @ 12,688,384   1,605,632
// y2     @ 14,294,016   401,408
// y3     @ 14,695,424   131,072
// concat @ 14,826,496   655,360      (part rows seeded with bias; part_gemm atomicAdds)
// w1h    @ 15,481,856   4,718,592    fp16 [9 tap][64 s][4 kg][128 n][16B]
// wt2t   @ 20,200,448   589,824
// wt3t   @ 20,790,272   589,824
// E      @ 21,380,096   39,321,600:  phase1 xh(19,660,800)+xl(19,660,800)
//                                    phase2 y1p 18 slices (28,901,376)
// F      @ 60,701,696:  phase1 rawh(12,845,056)+rawl(12,845,056) fp16
//                       phase2 abar(786,432) fp32
// end 86,391,808

typedef __attribute__((address_space(3))) unsigned int lds_u32;
typedef const __attribute__((address_space(1))) unsigned int glb_u32;
__device__ __forceinline__ void glds16(const void* g, void* l) {
    __builtin_amdgcn_global_load_lds((glb_u32*)g, (lds_u32*)l, 16, 0, 0);
}

// ================= prep_all: every input convert + inits, one launch =================
// wt1 branch: coalesced-read remap (72 consecutive floats/thread); others keep
// coalesced-write mappings (remap would 4x-amplify 39MB of writes).
__global__ __launch_bounds__(256)
void prep_all(const float* __restrict__ x, const float* __restrict__ bbw,
              const float* __restrict__ n1dw, const float* __restrict__ n2dw,
              const float* __restrict__ n3dw, const float* __restrict__ cnb,
              const float* __restrict__ bbb,
              half_t* __restrict__ xh, half_t* __restrict__ xl,
              half_t* __restrict__ bh, half_t* __restrict__ w1h,
              float* __restrict__ wt2t, float* __restrict__ wt3t,
              float* __restrict__ out, float* __restrict__ zpad,
              float* __restrict__ concat)
{
    const long t = (long)blockIdx.x * 256 + threadIdx.x;
    if (t < 1228800) {
        // x -> patchified swizzled fp16 hi/lo
        const int m = (int)(t % 3200), k8 = (int)(t / 3200);
        const int mt = m >> 7, mr = m & 127, s = k8 >> 2, kg = k8 & 3;
        const size_t dst = (((size_t)(mt * 96 + s) * 4 + kg) * 128 + mr) * 8;
        float f[8];
        if (m < 3136) {
            const int bq = m / 196, pos = m % 196, oy = pos / 14, ox = pos % 14;
            const int k = k8 * 8, c = k >> 10, r = (k >> 5) & 31, cc = k & 31;
            const float* p = x + ((size_t)(bq * 3 + c) * 448 + oy * 32 + r) * 448 + ox * 32 + cc;
            *(float4*)&f[0] = *(const float4*)p;
            *(float4*)&f[4] = *(const float4*)(p + 4);
        } else {
            #pragma unroll
            for (int j = 0; j < 8; ++j) f[j] = 0.f;
        }
        half8 h, l;
        #pragma unroll
        for (int j = 0; j < 8; ++j) {
            const half_t hh = (half_t)f[j];
            h[j] = hh;
            l[j] = (half_t)(f[j] - (float)hh);
        }
        *(half8*)(xh + dst) = h;
        *(half8*)(xl + dst) = l;
    } else if (t < 2015232) {
        // bb_w -> swizzled fp16 (hi only)
        const int t2 = (int)(t - 1228800);
        const int n = t2 % 2048, k8 = t2 / 2048;
        const float* p = bbw + (size_t)n * 3072 + k8 * 8;
        float f[8];
        *(float4*)&f[0] = *(const float4*)p;
        *(float4*)&f[4] = *(const float4*)(p + 4);
        const int nt = n >> 6, nr = n & 63, s = k8 >> 2, kg = k8 & 3;
        const size_t dst = (((size_t)(nt * 96 + s) * 4 + kg) * 64 + nr) * 8;
        half8 h;
        #pragma unroll
        for (int j = 0; j < 8; ++j) h[j] = (half_t)f[j];
        *(half8*)(bh + dst) = h;
    } else if (t < 2048000) {
        // wt1 swizzle fp16, COALESCED READS: thread = (n, ic8), 72 contiguous floats
        const int t2 = (int)(t - 2015232);     // [0, 32768)
        const int n = t2 >> 8, ic8 = t2 & 255;
        const int s = ic8 >> 2, kg = ic8 & 3;
        const float* src = n1dw + ((size_t)n * 2048 + ic8 * 8) * 9;
        float buf[72];
        #pragma unroll
        for (int i = 0; i < 18; ++i) *(float4*)&buf[i * 4] = *(const float4*)(src + i * 4);
        #pragma unroll
        for (int tap = 0; tap < 9; ++tap) {
            half8 h;
            #pragma unroll
            for (int j = 0; j < 8; ++j) h[j] = (half_t)buf[j * 9 + tap];
            const size_t dst = (((size_t)(tap * 64 + s) * 4 + kg) * 128 + n) * 8;
            *(half8*)(w1h + dst) = h;
        }
    } else if (t < 2195456) {
        const int t2 = (int)(t - 2048000);
        const int oc = t2 % 128, rest = t2 / 128, ic = rest % 128, tap = rest / 128;
        wt2t[(tap * 128 + ic) * 128 + oc] = n2dw[((size_t)oc * 128 + ic) * 9 + tap];
    } else if (t < 2342912) {
        const int t2 = (int)(t - 2195456);
        const int oc = t2 % 128, rest = t2 / 128, ic = rest % 128, tap = rest / 128;
        wt3t[(tap * 128 + ic) * 128 + oc] = n3dw[((size_t)oc * 128 + ic) * 9 + tap];
    } else if (t < 2346112) {
        const int i = (int)(t - 2342912);
        out[i] = cnb[i % 200];
    } else if (t < 2346368) {
        zpad[t - 2346112] = 0.f;
    } else if (t < 2477440) {
        const int i = (int)(t - 2346368);
        const int b = i >> 13, r = i & 8191;
        concat[(size_t)b * 10240 + r] = bbb[r & 2047];
    }
}

// ================= gemm_x: fp16 2-product 128Mx128N K=3072; out raw fp16 hi/lo + bias =======
__global__ __launch_bounds__(256)
void gemm_x(const half_t* __restrict__ Ah, const half_t* __restrict__ Al,
            const half_t* __restrict__ Bh, const float* __restrict__ bias,
            half_t* __restrict__ outh, half_t* __restrict__ outl)
{
    __shared__ __align__(16) char L[24576]; // Ahi 0 (8192), Alo 8192 (8192), B 16384 (8192)
    const int tid = threadIdx.x, lane = tid & 63, wv = tid >> 6;
    const int nt = blockIdx.x, mt = blockIdx.y;   // 16 x 25
    const int lm = lane & 15, quad = lane >> 4;
    const int wm = wv >> 1, wn = wv & 1;

    const char* gAh = (const char*)Ah + (size_t)mt * 96 * 8192 + lane * 16;
    const char* gAl = (const char*)Al + (size_t)mt * 96 * 8192 + lane * 16;
    const int bhalf = wv >> 1, bkg = (wv & 1) * 2;
    const char* gB = (const char*)Bh + (size_t)(2 * nt + bhalf) * 96 * 4096 + bkg * 1024 + lane * 16;

    int afo[4], bfo[4];
    #pragma unroll
    for (int i = 0; i < 4; ++i) afo[i] = quad * 2048 + (wm * 64 + i * 16 + lm) * 16;
    #pragma unroll
    for (int j = 0; j < 4; ++j) bfo[j] = 16384 + wn * 4096 + quad * 1024 + (j * 16 + lm) * 16;

    floatx4 acc[4][4];
    const floatx4 fz = {0.f, 0.f, 0.f, 0.f};
    #pragma unroll
    for (int i = 0; i < 4; ++i)
        #pragma unroll
        for (int j = 0; j < 4; ++j) acc[i][j] = fz;

    for (int s = 0; s < 96; ++s) {
        const size_t sa = (size_t)s * 8192;
        glds16(gAh + sa + (2 * wv) * 1024,     L + (2 * wv) * 1024);
        glds16(gAh + sa + (2 * wv + 1) * 1024, L + (2 * wv + 1) * 1024);
        glds16(gAl + sa + (2 * wv) * 1024,     L + 8192 + (2 * wv) * 1024);
        glds16(gAl + sa + (2 * wv + 1) * 1024, L + 8192 + (2 * wv + 1) * 1024);
        glds16(gB + (size_t)s * 4096,          L + 16384 + bhalf * 4096 + bkg * 1024);
        glds16(gB + (size_t)s * 4096 + 1024,   L + 16384 + bhalf * 4096 + (bkg + 1) * 1024);
        __syncthreads();
        half8 ah[4], al[4], bh[4];
        #pragma unroll
        for (int i = 0; i < 4; ++i) { ah[i] = *(const half8*)(L + afo[i]); al[i] = *(const half8*)(L + 8192 + afo[i]); }
        #pragma unroll
        for (int j = 0; j < 4; ++j) bh[j] = *(const half8*)(L + bfo[j]);
        #pragma unroll
        for (int i = 0; i < 4; ++i)
            #pragma unroll
            for (int j = 0; j < 4; ++j) {
                acc[i][j] = __builtin_amdgcn_mfma_f32_16x16x32_f16(ah[i], bh[j], acc[i][j], 0, 0, 0);
                acc[i][j] = __builtin_amdgcn_mfma_f32_16x16x32_f16(al[i], bh[j], acc[i][j], 0, 0, 0);
            }
        __syncthreads();
    }
    #pragma unroll
    for (int i = 0; i < 4; ++i) {
        const int m0 = mt * 128 + wm * 64 + i * 16 + quad * 4;
        #pragma unroll
        for (int j = 0; j < 4; ++j) {
            const int n = nt * 128 + wn * 64 + j * 16 + lm;
            const float bv = bias[n];
            #pragma unroll
            for (int r = 0; r < 4; ++r) {
                const int mm = m0 + r;
                if (mm < 3136) {
                    const float v = acc[i][j][r] + bv;
                    const half_t h = (half_t)v;
                    outh[(size_t)mm * 2048 + n] = h;
                    outl[(size_t)mm * 2048 + n] = (half_t)(v - (float)h);
                }
            }
        }
    }
}

// ================= gemm_nav: fp16 2-product 128Mx128N, K=1024 per (tap,ks), y1p 18 slices ===
__global__ __launch_bounds__(256)
void gemm_nav(const half_t* __restrict__ rawh, const half_t* __restrict__ rawl,
              const half_t* __restrict__ Bh, const char* __restrict__ zpad,
              float* __restrict__ y1p)
{
    __shared__ __align__(16) char L[24576]; // Ahi 0, Alo 8192, B 16384
    const int tid = threadIdx.x, lane = tid & 63, wv = tid >> 6;
    const int tx = blockIdx.x;   // 18: tap = tx>>1, ks = tx&1
    const int tap = tx >> 1, ks = tx & 1;
    const int mt = blockIdx.y;   // 25
    const int lm = lane & 15, quad = lane >> 4;
    const int wm = wv >> 1, wn = wv & 1;

    const char* baseH[2];
    const char* baseL[2];
    int stp[2];
    #pragma unroll
    for (int rh = 0; rh < 2; ++rh) {
        const int grow = mt * 128 + rh * 64 + lane;
        const int b = grow / 196, pos = grow % 196, oy = pos / 14, ox = pos % 14;
        const int iy = oy + tap / 3 - 1, ix = ox + tap % 3 - 1;
        const bool av = (grow < 3136) && iy >= 0 && iy < 14 && ix >= 0 && ix < 14;
        const size_t rowoff = av ? ((size_t)(b * 196 + iy * 14 + ix)) * 4096 + ks * 2048 + wv * 16 : 0;
        baseH[rh] = av ? (const char*)rawh + rowoff : zpad;
        baseL[rh] = av ? (const char*)rawl + rowoff : zpad;
        stp[rh] = av ? 64 : 0;
    }
    const char* gB = (const char*)Bh + (size_t)tap * 524288 + (size_t)ks * 32 * 8192 + lane * 16;

    int afo[4], bfo[4];
    #pragma unroll
    for (int i = 0; i < 4; ++i) afo[i] = quad * 2048 + (wm * 64 + i * 16 + lm) * 16;
    #pragma unroll
    for (int j = 0; j < 4; ++j) bfo[j] = 16384 + quad * 2048 + (wn * 64 + j * 16 + lm) * 16;

    floatx4 acc[4][4];
    const floatx4 fz = {0.f, 0.f, 0.f, 0.f};
    #pragma unroll
    for (int i = 0; i < 4; ++i)
        #pragma unroll
        for (int j = 0; j < 4; ++j) acc[i][j] = fz;

    for (int s = 0; s < 32; ++s) {
        glds16(baseH[0] + s * stp[0], L + wv * 2048);
        glds16(baseH[1] + s * stp[1], L + wv * 2048 + 1024);
        glds16(baseL[0] + s * stp[0], L + 8192 + wv * 2048);
        glds16(baseL[1] + s * stp[1], L + 8192 + wv * 2048 + 1024);
        glds16(gB + (size_t)s * 8192 + (2 * wv) * 1024,     L + 16384 + (2 * wv) * 1024);
        glds16(gB + (size_t)s * 8192 + (2 * wv + 1) * 1024, L + 16384 + (2 * wv + 1) * 1024);
        __syncthreads();
        half8 ah[4], al[4], bh[4];
        #pragma unroll
        for (int i = 0; i < 4; ++i) { ah[i] = *(const half8*)(L + afo[i]); al[i] = *(const half8*)(L + 8192 + afo[i]); }
        #pragma unroll
        for (int j = 0; j < 4; ++j) bh[j] = *(const half8*)(L + bfo[j]);
        #pragma unroll
        for (int i = 0; i < 4; ++i)
            #pragma unroll
            for (int j = 0; j < 4; ++j) {
                acc[i][j] = __builtin_amdgcn_mfma_f32_16x16x32_f16(ah[i], bh[j], acc[i][j], 0, 0, 0);
                acc[i][j] = __builtin_amdgcn_mfma_f32_16x16x32_f16(al[i], bh[j], acc[i][j], 0, 0, 0);
            }
        __syncthreads();
    }
    #pragma unroll
    for (int i = 0; i < 4; ++i) {
        const int m0 = mt * 128 + wm * 64 + i * 16 + quad * 4;
        #pragma unroll
        for (int j = 0; j < 4; ++j) {
            const int n = wn * 64 + j * 16 + lm;
            #pragma unroll
            for (int r = 0; r < 4; ++r) {
                const int mm = m0 + r;
                if (mm < 3136)
                    y1p[((size_t)tx * 3136 + mm) * 128 + n] = acc[i][j][r];
            }
        }
    }
}

// ================= y1 reduce (18 slices) + bias + relu, fused with raw_mean =================
__global__ __launch_bounds__(256)
void y1r_rm(const float* __restrict__ y1p, const float* __restrict__ bias,
            float* __restrict__ y1,
            const half_t* __restrict__ rh, const half_t* __restrict__ rl,
            float* __restrict__ concat)
{
    if (blockIdx.x < 1568) {
        const int t = blockIdx.x * 256 + threadIdx.x;
        const int n = t & 127;
        float s = bias[n];
        #pragma unroll
        for (int ks = 0; ks < 18; ++ks) s += y1p[(size_t)ks * 3136 * 128 + t];
        y1[t] = fmaxf(s, 0.f);
    } else {
        const int t = (blockIdx.x - 1568) * 256 + threadIdx.x;
        if (t >= 16 * 2048) return;
        const int n = t & 2047, b = t >> 11;
        float s = 0.f;
        for (int p = 0; p < 196; ++p) {
            const size_t o = (size_t)(b * 196 + p) * 2048 + n;
            s += (float)rh[o] + (float)rl[o];
        }
        concat[(size_t)b * 10240 + 8192 + n] = s / 196.f;
    }
}

// ================= tidy_all: all 3 score levels in one launch =================
__global__ __launch_bounds__(256)
void tidy_all(const float* __restrict__ y1, const float* __restrict__ y2,
              const float* __restrict__ y3,
              const float* __restrict__ w1, const float* __restrict__ b1,
              const float* __restrict__ w2, const float* __restrict__ b2,
              const float* __restrict__ w3, const float* __restrict__ b3,
              float* __restrict__ scores)
{
    const int wid = (blockIdx.x * 256 + threadIdx.x) >> 6;
    const int lane = threadIdx.x & 63;
    if (wid >= 16 * 1614) return;
    const int b = wid / 1614, idx = wid % 1614;
    const float* in; const float* w; const float* bi; int ch;
    if (idx < 1176) {
        ch = idx / 196; in = y1 + (size_t)(b * 196 + idx % 196) * 128; w = w1; bi = b1;
    } else if (idx < 1470) {
        const int i2 = idx - 1176;
        ch = i2 / 49; in = y2 + (size_t)(b * 49 + i2 % 49) * 128; w = w2; bi = b2;
    } else {
        const int i3 = idx - 1470;
        ch = i3 / 16; in = y3 + (size_t)(b * 16 + i3 % 16) * 128; w = w3; bi = b3;
    }
    const float* wr = w + ch * 128;
    float acc = in[lane] * wr[lane] + in[lane + 64] * wr[lane + 64];
    #pragma unroll
    for (int s = 32; s > 0; s >>= 1) acc += __shfl_down(acc, s, 64);
    if (lane == 0) scores[b * 1614 + idx] = acc + bi[ch];
}

// ================= 3x3 stride-2 conv, wt layout [tap][ic][oc] =================
__global__ __launch_bounds__(256)
void conv_s2(const float* __restrict__ in, const float* __restrict__ wt,
             const float* __restrict__ bias, float* __restrict__ out,
             int Win, int Wout)
{
    const int t = blockIdx.x * 256 + threadIdx.x;
    const int oc = t & 127;
    const int pos = (t >> 7) % (Wout * Wout);
    const int b = t / (128 * Wout * Wout);
    if (b >= 16) return;
    const int oy = pos / Wout, ox = pos % Wout;
    float acc = bias[oc];
    for (int dy = 0; dy < 3; ++dy) {
        const int y = oy * 2 + dy - 1;
        if (y < 0 || y >= Win) continue;
        for (int dx = 0; dx < 3; ++dx) {
            const int x = ox * 2 + dx - 1;
            if (x < 0 || x >= Win) continue;
            const float* ip = in + (size_t)(b * Win * Win + y * Win + x) * 128;
            const float* wp = wt + (size_t)(dy * 3 + dx) * 16384 + oc;
            for (int ic = 0; ic < 128; ++ic)
                acc += ip[ic] * wp[ic * 128];
        }
    }
    out[(size_t)(b * Wout * Wout + pos) * 128 + oc] = fmaxf(acc, 0.f);
}

// ================= NMS =================
__global__ __launch_bounds__(256)
void nms(const float* __restrict__ scores, const int* __restrict__ anchors,
         int* __restrict__ top_idx)
{
    __shared__ float sc[1614];
    __shared__ unsigned char valid[1614];
    __shared__ float rv[256];
    __shared__ int ri[256];
    const int b = blockIdx.x, tid = threadIdx.x;
    for (int i = tid; i < 1614; i += 256) { sc[i] = scores[b * 1614 + i]; valid[i] = 1; }
    __syncthreads();
    for (int r = 0; r < 4; ++r) {
        float bv = -INFINITY; int bi = 0x7fffffff;
        for (int i = tid; i < 1614; i += 256) {
            const float v = valid[i] ? sc[i] : -INFINITY;
            if (v > bv || (v == bv && i < bi)) { bv = v; bi = i; }
        }
        rv[tid] = bv; ri[tid] = bi;
        __syncthreads();
        for (int s = 128; s > 0; s >>= 1) {
            if (tid < s) {
                const float v2 = rv[tid + s]; const int i2 = ri[tid + s];
                if (v2 > rv[tid] || (v2 == rv[tid] && i2 < ri[tid])) { rv[tid] = v2; ri[tid] = i2; }
            }
            __syncthreads();
        }
        const int pick = ri[0];
        if (tid == 0) top_idx[b * 4 + r] = pick;
        const float py0 = (float)anchors[pick * 4 + 0], px0 = (float)anchors[pick * 4 + 1];
        const float py1 = (float)anchors[pick * 4 + 2], px1 = (float)anchors[pick * 4 + 3];
        const float pa = (py1 - py0) * (px1 - px0);
        for (int i = tid; i < 1614; i += 256) {
            const float y0 = (float)anchors[i * 4 + 0], x0 = (float)anchors[i * 4 + 1];
            const float y1 = (float)anchors[i * 4 + 2], x1 = (float)anchors[i * 4 + 3];
            const float ih = fminf(y1, py1) - fmaxf(y0, py0);
            const float iw = fminf(x1, px1) - fmaxf(x0, px0);
            const float inter = (ih < 0.f || iw < 0.f) ? 0.f : ih * iw;
            const float area = (y1 - y0) * (x1 - x0);
            const float iou = inter / ((area + pa) - inter);
            if (iou >= 0.25f) valid[i] = 0;
        }
        __syncthreads();
    }
}

// ================= crop_mean: mean over 49 positions of patchified crop ================
__global__ __launch_bounds__(256)
void crop_mean(const float* __restrict__ x, const int* __restrict__ anchors,
               const int* __restrict__ top_idx, float* __restrict__ abar)
{
    __shared__ float red[256];
    const int bi = blockIdx.x;               // 6144
    const int q = bi / 96, rem = bi % 96, c = rem >> 5, r = rem & 31;
    const int tid = threadIdx.x;
    const int cc = tid & 31, ps = tid >> 5;
    const int idx = top_idx[q];
    const int y0 = anchors[idx * 4 + 0], x0 = anchors[idx * 4 + 1];
    const int y1 = anchors[idx * 4 + 2], x1 = anchors[idx * 4 + 3];
    const float hh = (float)(y1 - y0), ww = (float)(x1 - x0);
    const float* xb = x + (size_t)((q >> 2) * 3 + c) * 200704;
    float acc = 0.f;
    for (int p = ps; p < 49; p += 8) {
        const int oy = p / 7, ox = p % 7;
        const int typ = oy * 32 + r;
        const int txp = ox * 32 + cc;
        const float sy = (float)typ * (hh - 1.0f) / 223.0f;
        const float fy = floorf(sy);
        const float wy = sy - fy;
        const int iy0 = y0 + (int)fy;
        const int iy1 = min(iy0 + 1, y1 - 1);
        const float sx = (float)txp * (ww - 1.0f) / 223.0f;
        const float fx = floorf(sx);
        const float wx = sx - fx;
        const int ix0 = x0 + (int)fx;
        const int ix1 = min(ix0 + 1, x1 - 1);
        const int ry0 = iy0 - 224, ry1 = iy1 - 224;
        const int rx0 = ix0 - 224, rx1 = ix1 - 224;
        const bool vy0 = (ry0 >= 0 && ry0 < 448), vy1 = (ry1 >= 0 && ry1 < 448);
        const bool vx0 = (rx0 >= 0 && rx0 < 448), vx1 = (rx1 >= 0 && rx1 < 448);
        const float v00 = (vy0 && vx0) ? xb[(size_t)ry0 * 448 + rx0] : 0.f;
        const float v01 = (vy0 && vx1) ? xb[(size_t)ry0 * 448 + rx1] : 0.f;
        const float v10 = (vy1 && vx0) ? xb[(size_t)ry1 * 448 + rx0] : 0.f;
        const float v11 = (vy1 && vx1) ? xb[(size_t)ry1 * 448 + rx1] : 0.f;
        const float top = v00 * (1.f - wx) + v01 * wx;
        const float bot = v10 * (1.f - wx) + v11 * wx;
        acc += top * (1.f - wy) + bot * wy;
    }
    red[tid] = acc;
    __syncthreads();
    if (tid < 32) {
        float s = 0.f;
        #pragma unroll
        for (int k = 0; k < 8; ++k) s += red[tid + 32 * k];
        abar[(size_t)q * 3072 + c * 1024 + r * 32 + cc] = s * (1.f / 49.f);
    }
}

// ================= part_gemm: Abar(64x3072) x bbwh, grid (32 nt, 8 ks), atomic into concat ==
__global__ __launch_bounds__(256)
void part_gemm(const float* __restrict__ abar, const half_t* __restrict__ Bh,
               float* __restrict__ concat)
{
    __shared__ __align__(16) char L[12288]; // Ah 0 (4096), Al 4096, B 8192 (4096)
    const int tid = threadIdx.x, lane = tid & 63, wv = tid >> 6;
    const int lm = lane & 15, quad = lane >> 4;
    const int nt = blockIdx.x, ks = blockIdx.y;
    const char* gBh = (const char*)Bh + ((size_t)nt * 96 + ks * 12) * 4096 + lane * 16;
    const int am = tid & 63, akg = tid >> 6;

    floatx4 acc[4], accl[4];
    const floatx4 fz = {0.f, 0.f, 0.f, 0.f};
    #pragma unroll
    for (int j = 0; j < 4; ++j) { acc[j] = fz; accl[j] = fz; }

    for (int s = 0; s < 12; ++s) {
        {
            const float* pa = abar + (size_t)am * 3072 + (ks * 12 + s) * 32 + akg * 8;
            float f[8];
            *(float4*)&f[0] = *(const float4*)pa;
            *(float4*)&f[4] = *(const float4*)(pa + 4);
            half8 h, l;
            #pragma unroll
            for (int j = 0; j < 8; ++j) {
                const half_t hh = (half_t)f[j];
                h[j] = hh;
                l[j] = (half_t)(f[j] - (float)hh);
            }
            *(half8*)(L + (akg * 64 + am) * 16) = h;
            *(half8*)(L + 4096 + (akg * 64 + am) * 16) = l;
        }
        glds16(gBh + (size_t)s * 4096 + wv * 1024, L + 8192 + wv * 1024);
        __syncthreads();
        half8 ah, al, bh[4];
        ah = *(const half8*)(L + (quad * 64 + wv * 16 + lm) * 16);
        al = *(const half8*)(L + 4096 + (quad * 64 + wv * 16 + lm) * 16);
        #pragma unroll
        for (int j = 0; j < 4; ++j) bh[j] = *(const half8*)(L + 8192 + (quad * 64 + j * 16 + lm) * 16);
        #pragma unroll
        for (int j = 0; j < 4; ++j) {
            acc[j]  = __builtin_amdgcn_mfma_f32_16x16x32_f16(ah, bh[j], acc[j], 0, 0, 0);
            accl[j] = __builtin_amdgcn_mfma_f32_16x16x32_f16(al, bh[j], accl[j], 0, 0, 0);
        }
        __syncthreads();
    }
    #pragma unroll
    for (int j = 0; j < 4; ++j) {
        const int n = nt * 64 + j * 16 + lm;
        #pragma unroll
        for (int r = 0; r < 4; ++r) {
            const int m = wv * 16 + quad * 4 + r;
            atomicAdd(concat + (size_t)(m >> 2) * 10240 + (m & 3) * 2048 + n,
                      acc[j][r] + accl[j][r]);
        }
    }
}

// ================= classifier GEMM: 25 n-chunks x 32 k-splits, LDS-tiled =================
__global__ __launch_bounds__(256)
void cls_gemm(const float* __restrict__ concat, const float* __restrict__ w,
              float* __restrict__ out)
{
    __shared__ float ws_[8 * 321];
    __shared__ float cs_[16 * 321];
    __shared__ float red[256];
    const int nchunk = blockIdx.x, ks = blockIdx.y;
    const int tid = threadIdx.x;
    for (int i = tid; i < 2560; i += 256) {
        const int r = i / 320, k = i % 320;
        ws_[r * 321 + k] = w[(size_t)(nchunk * 8 + r) * 10240 + ks * 320 + k];
    }
    for (int i = tid; i < 5120; i += 256) {
        const int r = i / 320, k = i % 320;
        cs_[r * 321 + k] = concat[(size_t)r * 10240 + ks * 320 + k];
    }
    __syncthreads();
    const int b = tid & 15, c = (tid >> 4) & 7, hf = tid >> 7;
    const float* cp = cs_ + b * 321 + hf * 160;
    const float* wp = ws_ + c * 321 + hf * 160;
    float a = 0.f;
    #pragma unroll 8
    for (int k = 0; k < 160; ++k) a += cp[k] * wp[k];
    red[tid] = a;
    __syncthreads();
    if (tid < 128) atomicAdd(out + b * 200 + nchunk * 8 + c, red[tid] + red[tid + 128]);
}

extern "C" void kernel_launch(void* const* d_in, const int* in_sizes, int n_in,
                              void* d_out, int out_size, void* d_ws, size_t ws_size,
                              hipStream_t stream)
{
    const float* x     = (const float*)d_in[0];
    const float* bb_w  = (const float*)d_in[1];
    const float* bb_b  = (const float*)d_in[2];
    const float* n1_dw = (const float*)d_in[3];
    const float* n1_db = (const float*)d_in[4];
    const float* n1_tw = (const float*)d_in[5];
    const float* n1_tb = (const float*)d_in[6];
    const float* n2_dw = (const float*)d_in[7];
    const float* n2_db = (const float*)d_in[8];
    const float* n2_tw = (const float*)d_in[9];
    const float* n2_tb = (const float*)d_in[10];
    const float* n3_dw = (const float*)d_in[11];
    const float* n3_db = (const float*)d_in[12];
    const float* n3_tw = (const float*)d_in[13];
    const float* n3_tb = (const float*)d_in[14];
    const float* cn_w  = (const float*)d_in[15];
    const float* cn_b  = (const float*)d_in[16];
    const int*   anchors = (const int*)d_in[17];
    float* out = (float*)d_out;
    char* W = (char*)d_ws;

    half_t* bbwh  = (half_t*)(W + 0);
    float*  zpad  = (float*)(W + 12582912);
    int*    topidx= (int*)(W + 12583936);
    float*  scores= (float*)(W + 12584960);
    float*  y1    = (float*)(W + 12688384);
    float*  y2    = (float*)(W + 14294016);
    float*  y3    = (float*)(W + 14695424);
    float*  concat= (float*)(W + 14826496);
    half_t* w1h   = (half_t*)(W + 15481856);
    float*  wt2t  = (float*)(W + 20200448);
    float*  wt3t  = (float*)(W + 20790272);
    char* E = W + 21380096;
    half_t* xh    = (half_t*)E;
    half_t* xl    = (half_t*)(E + 19660800);
    float*  y1p   = (float*)E;
    char* F = W + 60701696;
    half_t* rawh  = (half_t*)F;
    half_t* rawl  = (half_t*)(F + 12845056);
    float*  abar  = (float*)F;   // alias: raw dead after gemm_nav + y1r_rm

    prep_all<<<9678, 256, 0, stream>>>(x, bb_w, n1_dw, n2_dw, n3_dw, cn_b, bb_b,
                                       xh, xl, bbwh, w1h, wt2t, wt3t, out, zpad, concat);

    gemm_x<<<dim3(16, 25), 256, 0, stream>>>(xh, xl, bbwh, bb_b, rawh, rawl);
    gemm_nav<<<dim3(18, 25), 256, 0, stream>>>(rawh, rawl, w1h, (const char*)zpad, y1p);
    y1r_rm<<<1696, 256, 0, stream>>>(y1p, n1_db, y1, rawh, rawl, concat);

    conv_s2<<<392, 256, 0, stream>>>(y1, wt2t, n2_db, y2, 14, 7);
    conv_s2<<<128, 256, 0, stream>>>(y2, wt3t, n3_db, y3, 7, 4);
    tidy_all<<<6456, 256, 0, stream>>>(y1, y2, y3, n1_tw, n1_tb, n2_tw, n2_tb,
                                       n3_tw, n3_tb, scores);

    nms<<<16, 256, 0, stream>>>(scores, anchors, topidx);
    crop_mean<<<6144, 256, 0, stream>>>(x, anchors, topidx, abar);

    part_gemm<<<dim3(32, 8), 256, 0, stream>>>(abar, bbwh, concat);
    cls_gemm<<<dim3(25, 32), 256, 0, stream>>>(concat, cn_w, out);
}

// Round 10
// 455.586 us; speedup vs baseline: 1.0272x; 1.0272x over previous
//
#include <hip/hip_runtime.h>
#include <cstdint>
#include <math.h>

typedef _Float16 half_t;
typedef __attribute__((ext_vector_type(8))) _Float16 half8;
typedef __attribute__((ext_vector_type(4))) float floatx4;

// ---------------- workspace byte layout ----------------
// bbwh   @ 0            12,582,912   fp16 [32 nt][96 s][4 kg][64 n][16B]
// zpad   @ 12,582,912   1,024
// topidx @ 12,583,936   1,024
// scores @ 12,584,960   103,424
// y1     @ 12,688,384   1,605,632
// y2     @ 14,294,016   401,408
// y3     @ 14,695,424   131,072
// concat @ 14,826,496   655,360      (part rows bias-seeded, raw rows 0-seeded; atomics add)
// w1h    @ 15,481,856   4,718,592    fp16 [9 tap][64 s][4 kg][128 n][16B]
// wt2t   @ 20,200,448   589,824
// wt3t   @ 20,790,272   589,824
// E      @ 21,380,096   39,321,600:  phase1 xh(19,660,800)+xl(19,660,800)
//                                    phase2 y1p 18 slices (28,901,376)
// F      @ 60,701,696:  phase1 rawh(12,845,056)+rawl(12,845,056) fp16
//                       phase2 abar(786,432) fp32
// end 86,391,808

typedef __attribute__((address_space(3))) unsigned int lds_u32;
typedef const __attribute__((address_space(1))) unsigned int glb_u32;
__device__ __forceinline__ void glds16(const void* g, void* l) {
    __builtin_amdgcn_global_load_lds((glb_u32*)g, (lds_u32*)l, 16, 0, 0);
}

// ================= prep_all: every input convert + inits, one launch =================
// bbw branch now k8-fastest => coalesced 25MB first-touch reads (4x write amp on 12.6MB is cheaper).
__global__ __launch_bounds__(256)
void prep_all(const float* __restrict__ x, const float* __restrict__ bbw,
              const float* __restrict__ n1dw, const float* __restrict__ n2dw,
              const float* __restrict__ n3dw, const float* __restrict__ cnb,
              const float* __restrict__ bbb,
              half_t* __restrict__ xh, half_t* __restrict__ xl,
              half_t* __restrict__ bh, half_t* __restrict__ w1h,
              float* __restrict__ wt2t, float* __restrict__ wt3t,
              float* __restrict__ out, float* __restrict__ zpad,
              float* __restrict__ concat)
{
    const long t = (long)blockIdx.x * 256 + threadIdx.x;
    if (t < 1228800) {
        // x -> patchified swizzled fp16 hi/lo (writes coalesced; reads 4x-amp on L3-resident x)
        const int m = (int)(t % 3200), k8 = (int)(t / 3200);
        const int mt = m >> 7, mr = m & 127, s = k8 >> 2, kg = k8 & 3;
        const size_t dst = (((size_t)(mt * 96 + s) * 4 + kg) * 128 + mr) * 8;
        float f[8];
        if (m < 3136) {
            const int bq = m / 196, pos = m % 196, oy = pos / 14, ox = pos % 14;
            const int k = k8 * 8, c = k >> 10, r = (k >> 5) & 31, cc = k & 31;
            const float* p = x + ((size_t)(bq * 3 + c) * 448 + oy * 32 + r) * 448 + ox * 32 + cc;
            *(float4*)&f[0] = *(const float4*)p;
            *(float4*)&f[4] = *(const float4*)(p + 4);
        } else {
            #pragma unroll
            for (int j = 0; j < 8; ++j) f[j] = 0.f;
        }
        half8 h, l;
        #pragma unroll
        for (int j = 0; j < 8; ++j) {
            const half_t hh = (half_t)f[j];
            h[j] = hh;
            l[j] = (half_t)(f[j] - (float)hh);
        }
        *(half8*)(xh + dst) = h;
        *(half8*)(xl + dst) = l;
    } else if (t < 2015232) {
        // bb_w -> swizzled fp16, COALESCED reads: thread = (n, k8 fastest)
        const int t2 = (int)(t - 1228800);
        const int n = t2 / 384, k8 = t2 % 384;
        const float* p = bbw + (size_t)n * 3072 + k8 * 8;
        float f[8];
        *(float4*)&f[0] = *(const float4*)p;
        *(float4*)&f[4] = *(const float4*)(p + 4);
        const int nt = n >> 6, nr = n & 63, s = k8 >> 2, kg = k8 & 3;
        const size_t dst = (((size_t)(nt * 96 + s) * 4 + kg) * 64 + nr) * 8;
        half8 h;
        #pragma unroll
        for (int j = 0; j < 8; ++j) h[j] = (half_t)f[j];
        *(half8*)(bh + dst) = h;
    } else if (t < 2048000) {
        // wt1 swizzle fp16, coalesced reads: thread = (n, ic8), 72 contiguous floats
        const int t2 = (int)(t - 2015232);     // [0, 32768)
        const int n = t2 >> 8, ic8 = t2 & 255;
        const int s = ic8 >> 2, kg = ic8 & 3;
        const float* src = n1dw + ((size_t)n * 2048 + ic8 * 8) * 9;
        float buf[72];
        #pragma unroll
        for (int i = 0; i < 18; ++i) *(float4*)&buf[i * 4] = *(const float4*)(src + i * 4);
        #pragma unroll
        for (int tap = 0; tap < 9; ++tap) {
            half8 h;
            #pragma unroll
            for (int j = 0; j < 8; ++j) h[j] = (half_t)buf[j * 9 + tap];
            const size_t dst = (((size_t)(tap * 64 + s) * 4 + kg) * 128 + n) * 8;
            *(half8*)(w1h + dst) = h;
        }
    } else if (t < 2195456) {
        const int t2 = (int)(t - 2048000);
        const int oc = t2 % 128, rest = t2 / 128, ic = rest % 128, tap = rest / 128;
        wt2t[(tap * 128 + ic) * 128 + oc] = n2dw[((size_t)oc * 128 + ic) * 9 + tap];
    } else if (t < 2342912) {
        const int t2 = (int)(t - 2195456);
        const int oc = t2 % 128, rest = t2 / 128, ic = rest % 128, tap = rest / 128;
        wt3t[(tap * 128 + ic) * 128 + oc] = n3dw[((size_t)oc * 128 + ic) * 9 + tap];
    } else if (t < 2346112) {
        const int i = (int)(t - 2342912);
        out[i] = cnb[i % 200];
    } else if (t < 2346368) {
        zpad[t - 2346112] = 0.f;
    } else if (t < 2510208) {
        // seed ALL of concat: part rows (r<8192) with bias, raw rows (r>=8192) with 0
        const int i = (int)(t - 2346368);      // [0, 163840) = 16*10240
        const int r = i % 10240;
        concat[i] = (r < 8192) ? bbb[r & 2047] : 0.f;
    }
}

// ================= gemm_x: fp16 2-product 128Mx128N K=3072; out raw fp16 hi/lo + bias =======
__global__ __launch_bounds__(256)
void gemm_x(const half_t* __restrict__ Ah, const half_t* __restrict__ Al,
            const half_t* __restrict__ Bh, const float* __restrict__ bias,
            half_t* __restrict__ outh, half_t* __restrict__ outl)
{
    __shared__ __align__(16) char L[24576]; // Ahi 0 (8192), Alo 8192 (8192), B 16384 (8192)
    const int tid = threadIdx.x, lane = tid & 63, wv = tid >> 6;
    const int nt = blockIdx.x, mt = blockIdx.y;   // 16 x 25
    const int lm = lane & 15, quad = lane >> 4;
    const int wm = wv >> 1, wn = wv & 1;

    const char* gAh = (const char*)Ah + (size_t)mt * 96 * 8192 + lane * 16;
    const char* gAl = (const char*)Al + (size_t)mt * 96 * 8192 + lane * 16;
    const int bhalf = wv >> 1, bkg = (wv & 1) * 2;
    const char* gB = (const char*)Bh + (size_t)(2 * nt + bhalf) * 96 * 4096 + bkg * 1024 + lane * 16;

    int afo[4], bfo[4];
    #pragma unroll
    for (int i = 0; i < 4; ++i) afo[i] = quad * 2048 + (wm * 64 + i * 16 + lm) * 16;
    #pragma unroll
    for (int j = 0; j < 4; ++j) bfo[j] = 16384 + wn * 4096 + quad * 1024 + (j * 16 + lm) * 16;

    floatx4 acc[4][4];
    const floatx4 fz = {0.f, 0.f, 0.f, 0.f};
    #pragma unroll
    for (int i = 0; i < 4; ++i)
        #pragma unroll
        for (int j = 0; j < 4; ++j) acc[i][j] = fz;

    for (int s = 0; s < 96; ++s) {
        const size_t sa = (size_t)s * 8192;
        glds16(gAh + sa + (2 * wv) * 1024,     L + (2 * wv) * 1024);
        glds16(gAh + sa + (2 * wv + 1) * 1024, L + (2 * wv + 1) * 1024);
        glds16(gAl + sa + (2 * wv) * 1024,     L + 8192 + (2 * wv) * 1024);
        glds16(gAl + sa + (2 * wv + 1) * 1024, L + 8192 + (2 * wv + 1) * 1024);
        glds16(gB + (size_t)s * 4096,          L + 16384 + bhalf * 4096 + bkg * 1024);
        glds16(gB + (size_t)s * 4096 + 1024,   L + 16384 + bhalf * 4096 + (bkg + 1) * 1024);
        __syncthreads();
        half8 ah[4], al[4], bh[4];
        #pragma unroll
        for (int i = 0; i < 4; ++i) { ah[i] = *(const half8*)(L + afo[i]); al[i] = *(const half8*)(L + 8192 + afo[i]); }
        #pragma unroll
        for (int j = 0; j < 4; ++j) bh[j] = *(const half8*)(L + bfo[j]);
        #pragma unroll
        for (int i = 0; i < 4; ++i)
            #pragma unroll
            for (int j = 0; j < 4; ++j) {
                acc[i][j] = __builtin_amdgcn_mfma_f32_16x16x32_f16(ah[i], bh[j], acc[i][j], 0, 0, 0);
                acc[i][j] = __builtin_amdgcn_mfma_f32_16x16x32_f16(al[i], bh[j], acc[i][j], 0, 0, 0);
            }
        __syncthreads();
    }
    #pragma unroll
    for (int i = 0; i < 4; ++i) {
        const int m0 = mt * 128 + wm * 64 + i * 16 + quad * 4;
        #pragma unroll
        for (int j = 0; j < 4; ++j) {
            const int n = nt * 128 + wn * 64 + j * 16 + lm;
            const float bv = bias[n];
            #pragma unroll
            for (int r = 0; r < 4; ++r) {
                const int mm = m0 + r;
                if (mm < 3136) {
                    const float v = acc[i][j][r] + bv;
                    const half_t h = (half_t)v;
                    outh[(size_t)mm * 2048 + n] = h;
                    outl[(size_t)mm * 2048 + n] = (half_t)(v - (float)h);
                }
            }
        }
    }
}

// ================= gemm_nav: fp16 2-product 128Mx128N, K=1024 per (tap,ks), y1p 18 slices ===
__global__ __launch_bounds__(256)
void gemm_nav(const half_t* __restrict__ rawh, const half_t* __restrict__ rawl,
              const half_t* __restrict__ Bh, const char* __restrict__ zpad,
              float* __restrict__ y1p)
{
    __shared__ __align__(16) char L[24576]; // Ahi 0, Alo 8192, B 16384
    const int tid = threadIdx.x, lane = tid & 63, wv = tid >> 6;
    const int tx = blockIdx.x;   // 18: tap = tx>>1, ks = tx&1
    const int tap = tx >> 1, ks = tx & 1;
    const int mt = blockIdx.y;   // 25
    const int lm = lane & 15, quad = lane >> 4;
    const int wm = wv >> 1, wn = wv & 1;

    const char* baseH[2];
    const char* baseL[2];
    int stp[2];
    #pragma unroll
    for (int rh = 0; rh < 2; ++rh) {
        const int grow = mt * 128 + rh * 64 + lane;
        const int b = grow / 196, pos = grow % 196, oy = pos / 14, ox = pos % 14;
        const int iy = oy + tap / 3 - 1, ix = ox + tap % 3 - 1;
        const bool av = (grow < 3136) && iy >= 0 && iy < 14 && ix >= 0 && ix < 14;
        const size_t rowoff = av ? ((size_t)(b * 196 + iy * 14 + ix)) * 4096 + ks * 2048 + wv * 16 : 0;
        baseH[rh] = av ? (const char*)rawh + rowoff : zpad;
        baseL[rh] = av ? (const char*)rawl + rowoff : zpad;
        stp[rh] = av ? 64 : 0;
    }
    const char* gB = (const char*)Bh + (size_t)tap * 524288 + (size_t)ks * 32 * 8192 + lane * 16;

    int afo[4], bfo[4];
    #pragma unroll
    for (int i = 0; i < 4; ++i) afo[i] = quad * 2048 + (wm * 64 + i * 16 + lm) * 16;
    #pragma unroll
    for (int j = 0; j < 4; ++j) bfo[j] = 16384 + quad * 2048 + (wn * 64 + j * 16 + lm) * 16;

    floatx4 acc[4][4];
    const floatx4 fz = {0.f, 0.f, 0.f, 0.f};
    #pragma unroll
    for (int i = 0; i < 4; ++i)
        #pragma unroll
        for (int j = 0; j < 4; ++j) acc[i][j] = fz;

    for (int s = 0; s < 32; ++s) {
        glds16(baseH[0] + s * stp[0], L + wv * 2048);
        glds16(baseH[1] + s * stp[1], L + wv * 2048 + 1024);
        glds16(baseL[0] + s * stp[0], L + 8192 + wv * 2048);
        glds16(baseL[1] + s * stp[1], L + 8192 + wv * 2048 + 1024);
        glds16(gB + (size_t)s * 8192 + (2 * wv) * 1024,     L + 16384 + (2 * wv) * 1024);
        glds16(gB + (size_t)s * 8192 + (2 * wv + 1) * 1024, L + 16384 + (2 * wv + 1) * 1024);
        __syncthreads();
        half8 ah[4], al[4], bh[4];
        #pragma unroll
        for (int i = 0; i < 4; ++i) { ah[i] = *(const half8*)(L + afo[i]); al[i] = *(const half8*)(L + 8192 + afo[i]); }
        #pragma unroll
        for (int j = 0; j < 4; ++j) bh[j] = *(const half8*)(L + bfo[j]);
        #pragma unroll
        for (int i = 0; i < 4; ++i)
            #pragma unroll
            for (int j = 0; j < 4; ++j) {
                acc[i][j] = __builtin_amdgcn_mfma_f32_16x16x32_f16(ah[i], bh[j], acc[i][j], 0, 0, 0);
                acc[i][j] = __builtin_amdgcn_mfma_f32_16x16x32_f16(al[i], bh[j], acc[i][j], 0, 0, 0);
            }
        __syncthreads();
    }
    #pragma unroll
    for (int i = 0; i < 4; ++i) {
        const int m0 = mt * 128 + wm * 64 + i * 16 + quad * 4;
        #pragma unroll
        for (int j = 0; j < 4; ++j) {
            const int n = wn * 64 + j * 16 + lm;
            #pragma unroll
            for (int r = 0; r < 4; ++r) {
                const int mm = m0 + r;
                if (mm < 3136)
                    y1p[((size_t)tx * 3136 + mm) * 128 + n] = acc[i][j][r];
            }
        }
    }
}

// ========= y1 reduce (18 slices) + bias + relu, fused with raw_mean (512-block partials) =====
__global__ __launch_bounds__(256)
void y1r_rm(const float* __restrict__ y1p, const float* __restrict__ bias,
            float* __restrict__ y1,
            const half_t* __restrict__ rh, const half_t* __restrict__ rl,
            float* __restrict__ concat)
{
    if (blockIdx.x < 1568) {
        const int t = blockIdx.x * 256 + threadIdx.x;
        const int n = t & 127;
        float s = bias[n];
        #pragma unroll
        for (int ks = 0; ks < 18; ++ks) s += y1p[(size_t)ks * 3136 * 128 + t];
        y1[t] = fmaxf(s, 0.f);
    } else {
        const int t = (blockIdx.x - 1568) * 256 + threadIdx.x;  // [0, 131072)
        const int n = t & 2047, b = (t >> 11) & 15, pc = t >> 15;
        float s = 0.f;
        const int p0 = pc * 49;
        for (int p = p0; p < p0 + 49; ++p) {
            const size_t o = (size_t)(b * 196 + p) * 2048 + n;
            s += (float)rh[o] + (float)rl[o];
        }
        atomicAdd(concat + (size_t)b * 10240 + 8192 + n, s * (1.f / 196.f));
    }
}

// ================= tidy_all: all 3 score levels in one launch =================
__global__ __launch_bounds__(256)
void tidy_all(const float* __restrict__ y1, const float* __restrict__ y2,
              const float* __restrict__ y3,
              const float* __restrict__ w1, const float* __restrict__ b1,
              const float* __restrict__ w2, const float* __restrict__ b2,
              const float* __restrict__ w3, const float* __restrict__ b3,
              float* __restrict__ scores)
{
    const int wid = (blockIdx.x * 256 + threadIdx.x) >> 6;
    const int lane = threadIdx.x & 63;
    if (wid >= 16 * 1614) return;
    const int b = wid / 1614, idx = wid % 1614;
    const float* in; const float* w; const float* bi; int ch;
    if (idx < 1176) {
        ch = idx / 196; in = y1 + (size_t)(b * 196 + idx % 196) * 128; w = w1; bi = b1;
    } else if (idx < 1470) {
        const int i2 = idx - 1176;
        ch = i2 / 49; in = y2 + (size_t)(b * 49 + i2 % 49) * 128; w = w2; bi = b2;
    } else {
        const int i3 = idx - 1470;
        ch = i3 / 16; in = y3 + (size_t)(b * 16 + i3 % 16) * 128; w = w3; bi = b3;
    }
    const float* wr = w + ch * 128;
    float acc = in[lane] * wr[lane] + in[lane + 64] * wr[lane + 64];
    #pragma unroll
    for (int s = 32; s > 0; s >>= 1) acc += __shfl_down(acc, s, 64);
    if (lane == 0) scores[b * 1614 + idx] = acc + bi[ch];
}

// ================= 3x3 stride-2 conv, wt layout [tap][ic][oc] =================
__global__ __launch_bounds__(256)
void conv_s2(const float* __restrict__ in, const float* __restrict__ wt,
             const float* __restrict__ bias, float* __restrict__ out,
             int Win, int Wout)
{
    const int t = blockIdx.x * 256 + threadIdx.x;
    const int oc = t & 127;
    const int pos = (t >> 7) % (Wout * Wout);
    const int b = t / (128 * Wout * Wout);
    if (b >= 16) return;
    const int oy = pos / Wout, ox = pos % Wout;
    float acc = bias[oc];
    for (int dy = 0; dy < 3; ++dy) {
        const int y = oy * 2 + dy - 1;
        if (y < 0 || y >= Win) continue;
        for (int dx = 0; dx < 3; ++dx) {
            const int x = ox * 2 + dx - 1;
            if (x < 0 || x >= Win) continue;
            const float* ip = in + (size_t)(b * Win * Win + y * Win + x) * 128;
            const float* wp = wt + (size_t)(dy * 3 + dx) * 16384 + oc;
            for (int ic = 0; ic < 128; ++ic)
                acc += ip[ic] * wp[ic * 128];
        }
    }
    out[(size_t)(b * Wout * Wout + pos) * 128 + oc] = fmaxf(acc, 0.f);
}

// ================= NMS: register-resident scores/coords, 2 barriers per round =================
__global__ __launch_bounds__(256)
void nms(const float* __restrict__ scores, const int* __restrict__ anchors,
         int* __restrict__ top_idx)
{
    __shared__ float wv_v[4];
    __shared__ int wv_i[4];
    __shared__ int s_pick;
    const int b = blockIdx.x, tid = threadIdx.x;
    const int lane = tid & 63, wv = tid >> 6;
    float sc[7], ay0[7], ax0[7], ay1[7], ax1[7];
    unsigned int vmask = 0;
    #pragma unroll
    for (int j = 0; j < 7; ++j) {
        const int i = tid + j * 256;
        if (i < 1614) {
            sc[j]  = scores[b * 1614 + i];
            ay0[j] = (float)anchors[i * 4 + 0];
            ax0[j] = (float)anchors[i * 4 + 1];
            ay1[j] = (float)anchors[i * 4 + 2];
            ax1[j] = (float)anchors[i * 4 + 3];
            vmask |= 1u << j;
        }
    }
    for (int r = 0; r < 4; ++r) {
        float bv = -INFINITY; int bi = 0x7fffffff;
        #pragma unroll
        for (int j = 0; j < 7; ++j) {
            if (vmask & (1u << j)) {
                const float v = sc[j];
                const int i = tid + j * 256;
                if (v > bv || (v == bv && i < bi)) { bv = v; bi = i; }
            }
        }
        #pragma unroll
        for (int s = 32; s > 0; s >>= 1) {
            const float v2 = __shfl_down(bv, s, 64);
            const int   i2 = __shfl_down(bi, s, 64);
            if (v2 > bv || (v2 == bv && i2 < bi)) { bv = v2; bi = i2; }
        }
        if (lane == 0) { wv_v[wv] = bv; wv_i[wv] = bi; }
        __syncthreads();
        if (tid == 0) {
            float fv = wv_v[0]; int fi = wv_i[0];
            #pragma unroll
            for (int k = 1; k < 4; ++k)
                if (wv_v[k] > fv || (wv_v[k] == fv && wv_i[k] < fi)) { fv = wv_v[k]; fi = wv_i[k]; }
            s_pick = fi;
            top_idx[b * 4 + r] = fi;
        }
        __syncthreads();
        const int pick = s_pick;
        const float py0 = (float)anchors[pick * 4 + 0], px0 = (float)anchors[pick * 4 + 1];
        const float py1 = (float)anchors[pick * 4 + 2], px1 = (float)anchors[pick * 4 + 3];
        const float pa = (py1 - py0) * (px1 - px0);
        #pragma unroll
        for (int j = 0; j < 7; ++j) {
            if (vmask & (1u << j)) {
                const float ih = fminf(ay1[j], py1) - fmaxf(ay0[j], py0);
                const float iw = fminf(ax1[j], px1) - fmaxf(ax0[j], px0);
                const float inter = (ih < 0.f || iw < 0.f) ? 0.f : ih * iw;
                const float area = (ay1[j] - ay0[j]) * (ax1[j] - ax0[j]);
                const float iou = inter / ((area + pa) - inter);
                if (iou >= 0.25f) vmask &= ~(1u << j);
            }
        }
        // no extra barrier needed: next round's LDS writes are ordered by the two barriers above
    }
}

// ================= crop_mean: mean over 49 positions of patchified crop ================
__global__ __launch_bounds__(256)
void crop_mean(const float* __restrict__ x, const int* __restrict__ anchors,
               const int* __restrict__ top_idx, float* __restrict__ abar)
{
    __shared__ float red[256];
    const int bi = blockIdx.x;               // 6144
    const int q = bi / 96, rem = bi % 96, c = rem >> 5, r = rem & 31;
    const int tid = threadIdx.x;
    const int cc = tid & 31, ps = tid >> 5;
    const int idx = top_idx[q];
    const int y0 = anchors[idx * 4 + 0], x0 = anchors[idx * 4 + 1];
    const int y1 = anchors[idx * 4 + 2], x1 = anchors[idx * 4 + 3];
    const float hh = (float)(y1 - y0), ww = (float)(x1 - x0);
    const float* xb = x + (size_t)((q >> 2) * 3 + c) * 200704;
    float acc = 0.f;
    for (int p = ps; p < 49; p += 8) {
        const int oy = p / 7, ox = p % 7;
        const int typ = oy * 32 + r;
        const int txp = ox * 32 + cc;
        const float sy = (float)typ * (hh - 1.0f) / 223.0f;
        const float fy = floorf(sy);
        const float wy = sy - fy;
        const int iy0 = y0 + (int)fy;
        const int iy1 = min(iy0 + 1, y1 - 1);
        const float sx = (float)txp * (ww - 1.0f) / 223.0f;
        const float fx = floorf(sx);
        const float wx = sx - fx;
        const int ix0 = x0 + (int)fx;
        const int ix1 = min(ix0 + 1, x1 - 1);
        const int ry0 = iy0 - 224, ry1 = iy1 - 224;
        const int rx0 = ix0 - 224, rx1 = ix1 - 224;
        const bool vy0 = (ry0 >= 0 && ry0 < 448), vy1 = (ry1 >= 0 && ry1 < 448);
        const bool vx0 = (rx0 >= 0 && rx0 < 448), vx1 = (rx1 >= 0 && rx1 < 448);
        const float v00 = (vy0 && vx0) ? xb[(size_t)ry0 * 448 + rx0] : 0.f;
        const float v01 = (vy0 && vx1) ? xb[(size_t)ry0 * 448 + rx1] : 0.f;
        const float v10 = (vy1 && vx0) ? xb[(size_t)ry1 * 448 + rx0] : 0.f;
        const float v11 = (vy1 && vx1) ? xb[(size_t)ry1 * 448 + rx1] : 0.f;
        const float top = v00 * (1.f - wx) + v01 * wx;
        const float bot = v10 * (1.f - wx) + v11 * wx;
        acc += top * (1.f - wy) + bot * wy;
    }
    red[tid] = acc;
    __syncthreads();
    if (tid < 32) {
        float s = 0.f;
        #pragma unroll
        for (int k = 0; k < 8; ++k) s += red[tid + 32 * k];
        abar[(size_t)q * 3072 + c * 1024 + r * 32 + cc] = s * (1.f / 49.f);
    }
}

// ================= part_gemm: Abar(64x3072) x bbwh, grid (32 nt, 8 ks), atomic into concat ==
__global__ __launch_bounds__(256)
void part_gemm(const float* __restrict__ abar, const half_t* __restrict__ Bh,
               float* __restrict__ concat)
{
    __shared__ __align__(16) char L[12288]; // Ah 0 (4096), Al 4096, B 8192 (4096)
    const int tid = threadIdx.x, lane = tid & 63, wv = tid >> 6;
    const int lm = lane & 15, quad = lane >> 4;
    const int nt = blockIdx.x, ks = blockIdx.y;
    const char* gBh = (const char*)Bh + ((size_t)nt * 96 + ks * 12) * 4096 + lane * 16;
    const int am = tid & 63, akg = tid >> 6;

    floatx4 acc[4], accl[4];
    const floatx4 fz = {0.f, 0.f, 0.f, 0.f};
    #pragma unroll
    for (int j = 0; j < 4; ++j) { acc[j] = fz; accl[j] = fz; }

    for (int s = 0; s < 12; ++s) {
        {
            const float* pa = abar + (size_t)am * 3072 + (ks * 12 + s) * 32 + akg * 8;
            float f[8];
            *(float4*)&f[0] = *(const float4*)pa;
            *(float4*)&f[4] = *(const float4*)(pa + 4);
            half8 h, l;
            #pragma unroll
            for (int j = 0; j < 8; ++j) {
                const half_t hh = (half_t)f[j];
                h[j] = hh;
                l[j] = (half_t)(f[j] - (float)hh);
            }
            *(half8*)(L + (akg * 64 + am) * 16) = h;
            *(half8*)(L + 4096 + (akg * 64 + am) * 16) = l;
        }
        glds16(gBh + (size_t)s * 4096 + wv * 1024, L + 8192 + wv * 1024);
        __syncthreads();
        half8 ah, al, bh[4];
        ah = *(const half8*)(L + (quad * 64 + wv * 16 + lm) * 16);
        al = *(const half8*)(L + 4096 + (quad * 64 + wv * 16 + lm) * 16);
        #pragma unroll
        for (int j = 0; j < 4; ++j) bh[j] = *(const half8*)(L + 8192 + (quad * 64 + j * 16 + lm) * 16);
        #pragma unroll
        for (int j = 0; j < 4; ++j) {
            acc[j]  = __builtin_amdgcn_mfma_f32_16x16x32_f16(ah, bh[j], acc[j], 0, 0, 0);
            accl[j] = __builtin_amdgcn_mfma_f32_16x16x32_f16(al, bh[j], accl[j], 0, 0, 0);
        }
        __syncthreads();
    }
    #pragma unroll
    for (int j = 0; j < 4; ++j) {
        const int n = nt * 64 + j * 16 + lm;
        #pragma unroll
        for (int r = 0; r < 4; ++r) {
            const int m = wv * 16 + quad * 4 + r;
            atomicAdd(concat + (size_t)(m >> 2) * 10240 + (m & 3) * 2048 + n,
                      acc[j][r] + accl[j][r]);
        }
    }
}

// ================= classifier GEMM: 25 n-chunks x 32 k-splits, LDS-tiled =================
__global__ __launch_bounds__(256)
void cls_gemm(const float* __restrict__ concat, const float* __restrict__ w,
              float* __restrict__ out)
{
    __shared__ float ws_[8 * 321];
    __shared__ float cs_[16 * 321];
    __shared__ float red[256];
    const int nchunk = blockIdx.x, ks = blockIdx.y;
    const int tid = threadIdx.x;
    for (int i = tid; i < 2560; i += 256) {
        const int r = i / 320, k = i % 320;
        ws_[r * 321 + k] = w[(size_t)(nchunk * 8 + r) * 10240 + ks * 320 + k];
    }
    for (int i = tid; i < 5120; i += 256) {
        const int r = i / 320, k = i % 320;
        cs_[r * 321 + k] = concat[(size_t)r * 10240 + ks * 320 + k];
    }
    __syncthreads();
    const int b = tid & 15, c = (tid >> 4) & 7, hf = tid >> 7;
    const float* cp = cs_ + b * 321 + hf * 160;
    const float* wp = ws_ + c * 321 + hf * 160;
    float a = 0.f;
    #pragma unroll 8
    for (int k = 0; k < 160; ++k) a += cp[k] * wp[k];
    red[tid] = a;
    __syncthreads();
    if (tid < 128) atomicAdd(out + b * 200 + nchunk * 8 + c, red[tid] + red[tid + 128]);
}

extern "C" void kernel_launch(void* const* d_in, const int* in_sizes, int n_in,
                              void* d_out, int out_size, void* d_ws, size_t ws_size,
                              hipStream_t stream)
{
    const float* x     = (const float*)d_in[0];
    const float* bb_w  = (const float*)d_in[1];
    const float* bb_b  = (const float*)d_in[2];
    const float* n1_dw = (const float*)d_in[3];
    const float* n1_db = (const float*)d_in[4];
    const float* n1_tw = (const float*)d_in[5];
    const float* n1_tb = (const float*)d_in[6];
    const float* n2_dw = (const float*)d_in[7];
    const float* n2_db = (const float*)d_in[8];
    const float* n2_tw = (const float*)d_in[9];
    const float* n2_tb = (const float*)d_in[10];
    const float* n3_dw = (const float*)d_in[11];
    const float* n3_db = (const float*)d_in[12];
    const float* n3_tw = (const float*)d_in[13];
    const float* n3_tb = (const float*)d_in[14];
    const float* cn_w  = (const float*)d_in[15];
    const float* cn_b  = (const float*)d_in[16];
    const int*   anchors = (const int*)d_in[17];
    float* out = (float*)d_out;
    char* W = (char*)d_ws;

    half_t* bbwh  = (half_t*)(W + 0);
    float*  zpad  = (float*)(W + 12582912);
    int*    topidx= (int*)(W + 12583936);
    float*  scores= (float*)(W + 12584960);
    float*  y1    = (float*)(W + 12688384);
    float*  y2    = (float*)(W + 14294016);
    float*  y3    = (float*)(W + 14695424);
    float*  concat= (float*)(W + 14826496);
    half_t* w1h   = (half_t*)(W + 15481856);
    float*  wt2t  = (float*)(W + 20200448);
    float*  wt3t  = (float*)(W + 20790272);
    char* E = W + 21380096;
    half_t* xh    = (half_t*)E;
    half_t* xl    = (half_t*)(E + 19660800);
    float*  y1p   = (float*)E;
    char* F = W + 60701696;
    half_t* rawh  = (half_t*)F;
    half_t* rawl  = (half_t*)(F + 12845056);
    float*  abar  = (float*)F;   // alias: raw dead after gemm_nav + y1r_rm

    prep_all<<<9806, 256, 0, stream>>>(x, bb_w, n1_dw, n2_dw, n3_dw, cn_b, bb_b,
                                       xh, xl, bbwh, w1h, wt2t, wt3t, out, zpad, concat);

    gemm_x<<<dim3(16, 25), 256, 0, stream>>>(xh, xl, bbwh, bb_b, rawh, rawl);
    gemm_nav<<<dim3(18, 25), 256, 0, stream>>>(rawh, rawl, w1h, (const char*)zpad, y1p);
    y1r_rm<<<2080, 256, 0, stream>>>(y1p, n1_db, y1, rawh, rawl, concat);

    conv_s2<<<392, 256, 0, stream>>>(y1, wt2t, n2_db, y2, 14, 7);
    conv_s2<<<128, 256, 0, stream>>>(y2, wt3t, n3_db, y3, 7, 4);
    tidy_all<<<6456, 256, 0, stream>>>(y1, y2, y3, n1_tw, n1_tb, n2_tw, n2_tb,
                                       n3_tw, n3_tb, scores);

    nms<<<16, 256, 0, stream>>>(scores, anchors, topidx);
    crop_mean<<<6144, 256, 0, stream>>>(x, anchors, topidx, abar);

    part_gemm<<<dim3(32, 8), 256, 0, stream>>>(abar, bbwh, concat);
    cls_gemm<<<dim3(25, 32), 256, 0, stream>>>(concat, cn_w, out);
}

// Round 11
// 409.631 us; speedup vs baseline: 1.1425x; 1.1122x over previous
//
#include <hip/hip_runtime.h>
#include <cstdint>
#include <math.h>

typedef _Float16 half_t;
typedef __attribute__((ext_vector_type(8))) _Float16 half8;
typedef __attribute__((ext_vector_type(4))) float floatx4;

// ---------------- workspace byte layout ----------------
// bbwh   @ 0            12,582,912   fp16 [32 nt][96 s][4 kg][64 n][16B]
// zpad   @ 12,582,912   1,024
// topidx @ 12,583,936   1,024
// scores @ 12,584,960   103,424
// y1     @ 12,688,384   1,605,632
// y2     @ 14,294,016   401,408
// y3     @ 14,695,424   131,072
// concat @ 14,826,496   655,360      (part rows bias-seeded, raw rows 0-seeded; atomics add)
// w1h    @ 15,481,856   4,718,592    fp16 [9 tap][64 s][4 kg][128 n][16B]
// wt2t   @ 20,200,448   589,824
// wt3t   @ 20,790,272   589,824
// E      @ 21,380,096   39,321,600:  phase1 xh(19,660,800)
//                                    phase2 y1p 18 slices (28,901,376) (xh dead after gemm_x)
// F      @ 60,701,696:  phase1 rawh(12,845,056) fp16 single
//                       phase2 abar(786,432) fp32
// end 86,391,808

typedef __attribute__((address_space(3))) unsigned int lds_u32;
typedef const __attribute__((address_space(1))) unsigned int glb_u32;
__device__ __forceinline__ void glds16(const void* g, void* l) {
    __builtin_amdgcn_global_load_lds((glb_u32*)g, (lds_u32*)l, 16, 0, 0);
}

// ================= prep_all: every input convert + inits, one launch =================
__global__ __launch_bounds__(256)
void prep_all(const float* __restrict__ x, const float* __restrict__ bbw,
              const float* __restrict__ n1dw, const float* __restrict__ n2dw,
              const float* __restrict__ n3dw, const float* __restrict__ cnb,
              const float* __restrict__ bbb,
              half_t* __restrict__ xh,
              half_t* __restrict__ bh, half_t* __restrict__ w1h,
              float* __restrict__ wt2t, float* __restrict__ wt3t,
              float* __restrict__ out, float* __restrict__ zpad,
              float* __restrict__ concat)
{
    const long t = (long)blockIdx.x * 256 + threadIdx.x;
    if (t < 1228800) {
        // x -> patchified swizzled fp16 (single)
        const int m = (int)(t % 3200), k8 = (int)(t / 3200);
        const int mt = m >> 7, mr = m & 127, s = k8 >> 2, kg = k8 & 3;
        const size_t dst = (((size_t)(mt * 96 + s) * 4 + kg) * 128 + mr) * 8;
        float f[8];
        if (m < 3136) {
            const int bq = m / 196, pos = m % 196, oy = pos / 14, ox = pos % 14;
            const int k = k8 * 8, c = k >> 10, r = (k >> 5) & 31, cc = k & 31;
            const float* p = x + ((size_t)(bq * 3 + c) * 448 + oy * 32 + r) * 448 + ox * 32 + cc;
            *(float4*)&f[0] = *(const float4*)p;
            *(float4*)&f[4] = *(const float4*)(p + 4);
        } else {
            #pragma unroll
            for (int j = 0; j < 8; ++j) f[j] = 0.f;
        }
        half8 h;
        #pragma unroll
        for (int j = 0; j < 8; ++j) h[j] = (half_t)f[j];
        *(half8*)(xh + dst) = h;
    } else if (t < 2015232) {
        // bb_w -> swizzled fp16, coalesced reads: thread = (n, k8 fastest)
        const int t2 = (int)(t - 1228800);
        const int n = t2 / 384, k8 = t2 % 384;
        const float* p = bbw + (size_t)n * 3072 + k8 * 8;
        float f[8];
        *(float4*)&f[0] = *(const float4*)p;
        *(float4*)&f[4] = *(const float4*)(p + 4);
        const int nt = n >> 6, nr = n & 63, s = k8 >> 2, kg = k8 & 3;
        const size_t dst = (((size_t)(nt * 96 + s) * 4 + kg) * 64 + nr) * 8;
        half8 h;
        #pragma unroll
        for (int j = 0; j < 8; ++j) h[j] = (half_t)f[j];
        *(half8*)(bh + dst) = h;
    } else if (t < 2048000) {
        // wt1 swizzle fp16, coalesced reads: thread = (n, ic8), 72 contiguous floats
        const int t2 = (int)(t - 2015232);     // [0, 32768)
        const int n = t2 >> 8, ic8 = t2 & 255;
        const int s = ic8 >> 2, kg = ic8 & 3;
        const float* src = n1dw + ((size_t)n * 2048 + ic8 * 8) * 9;
        float buf[72];
        #pragma unroll
        for (int i = 0; i < 18; ++i) *(float4*)&buf[i * 4] = *(const float4*)(src + i * 4);
        #pragma unroll
        for (int tap = 0; tap < 9; ++tap) {
            half8 h;
            #pragma unroll
            for (int j = 0; j < 8; ++j) h[j] = (half_t)buf[j * 9 + tap];
            const size_t dst = (((size_t)(tap * 64 + s) * 4 + kg) * 128 + n) * 8;
            *(half8*)(w1h + dst) = h;
        }
    } else if (t < 2195456) {
        const int t2 = (int)(t - 2048000);
        const int oc = t2 % 128, rest = t2 / 128, ic = rest % 128, tap = rest / 128;
        wt2t[(tap * 128 + ic) * 128 + oc] = n2dw[((size_t)oc * 128 + ic) * 9 + tap];
    } else if (t < 2342912) {
        const int t2 = (int)(t - 2195456);
        const int oc = t2 % 128, rest = t2 / 128, ic = rest % 128, tap = rest / 128;
        wt3t[(tap * 128 + ic) * 128 + oc] = n3dw[((size_t)oc * 128 + ic) * 9 + tap];
    } else if (t < 2346112) {
        const int i = (int)(t - 2342912);
        out[i] = cnb[i % 200];
    } else if (t < 2346368) {
        zpad[t - 2346112] = 0.f;
    } else if (t < 2510208) {
        const int i = (int)(t - 2346368);      // [0, 163840)
        const int r = i % 10240;
        concat[i] = (r < 8192) ? bbb[r & 2047] : 0.f;
    }
}

// ================= gemm_x: fp16 single-product 128Mx128N K=3072; out raw fp16 + bias =======
__global__ __launch_bounds__(256)
void gemm_x(const half_t* __restrict__ Ah, const half_t* __restrict__ Bh,
            const float* __restrict__ bias, half_t* __restrict__ outh)
{
    __shared__ __align__(16) char L[16384]; // A 0 (8192), B 8192 (8192)
    const int tid = threadIdx.x, lane = tid & 63, wv = tid >> 6;
    const int nt = blockIdx.x, mt = blockIdx.y;   // 16 x 25
    const int lm = lane & 15, quad = lane >> 4;
    const int wm = wv >> 1, wn = wv & 1;

    const char* gAh = (const char*)Ah + (size_t)mt * 96 * 8192 + lane * 16;
    const int bhalf = wv >> 1, bkg = (wv & 1) * 2;
    const char* gB = (const char*)Bh + (size_t)(2 * nt + bhalf) * 96 * 4096 + bkg * 1024 + lane * 16;

    int afo[4], bfo[4];
    #pragma unroll
    for (int i = 0; i < 4; ++i) afo[i] = quad * 2048 + (wm * 64 + i * 16 + lm) * 16;
    #pragma unroll
    for (int j = 0; j < 4; ++j) bfo[j] = 8192 + wn * 4096 + quad * 1024 + (j * 16 + lm) * 16;

    floatx4 acc[4][4];
    const floatx4 fz = {0.f, 0.f, 0.f, 0.f};
    #pragma unroll
    for (int i = 0; i < 4; ++i)
        #pragma unroll
        for (int j = 0; j < 4; ++j) acc[i][j] = fz;

    for (int s = 0; s < 96; ++s) {
        const size_t sa = (size_t)s * 8192;
        glds16(gAh + sa + (2 * wv) * 1024,     L + (2 * wv) * 1024);
        glds16(gAh + sa + (2 * wv + 1) * 1024, L + (2 * wv + 1) * 1024);
        glds16(gB + (size_t)s * 4096,          L + 8192 + bhalf * 4096 + bkg * 1024);
        glds16(gB + (size_t)s * 4096 + 1024,   L + 8192 + bhalf * 4096 + (bkg + 1) * 1024);
        __syncthreads();
        half8 ah[4], bh[4];
        #pragma unroll
        for (int i = 0; i < 4; ++i) ah[i] = *(const half8*)(L + afo[i]);
        #pragma unroll
        for (int j = 0; j < 4; ++j) bh[j] = *(const half8*)(L + bfo[j]);
        #pragma unroll
        for (int i = 0; i < 4; ++i)
            #pragma unroll
            for (int j = 0; j < 4; ++j)
                acc[i][j] = __builtin_amdgcn_mfma_f32_16x16x32_f16(ah[i], bh[j], acc[i][j], 0, 0, 0);
        __syncthreads();
    }
    #pragma unroll
    for (int i = 0; i < 4; ++i) {
        const int m0 = mt * 128 + wm * 64 + i * 16 + quad * 4;
        #pragma unroll
        for (int j = 0; j < 4; ++j) {
            const int n = nt * 128 + wn * 64 + j * 16 + lm;
            const float bv = bias[n];
            #pragma unroll
            for (int r = 0; r < 4; ++r) {
                const int mm = m0 + r;
                if (mm < 3136)
                    outh[(size_t)mm * 2048 + n] = (half_t)(acc[i][j][r] + bv);
            }
        }
    }
}

// ================= gemm_nav: fp16 single-product 128Mx128N, K=1024 per (tap,ks) =============
__global__ __launch_bounds__(256)
void gemm_nav(const half_t* __restrict__ rawh, const half_t* __restrict__ Bh,
              const char* __restrict__ zpad, float* __restrict__ y1p)
{
    __shared__ __align__(16) char L[16384]; // A 0 (8192), B 8192 (8192)
    const int tid = threadIdx.x, lane = tid & 63, wv = tid >> 6;
    const int tx = blockIdx.x;   // 18: tap = tx>>1, ks = tx&1
    const int tap = tx >> 1, ks = tx & 1;
    const int mt = blockIdx.y;   // 25
    const int lm = lane & 15, quad = lane >> 4;
    const int wm = wv >> 1, wn = wv & 1;

    const char* baseH[2];
    int stp[2];
    #pragma unroll
    for (int rh = 0; rh < 2; ++rh) {
        const int grow = mt * 128 + rh * 64 + lane;
        const int b = grow / 196, pos = grow % 196, oy = pos / 14, ox = pos % 14;
        const int iy = oy + tap / 3 - 1, ix = ox + tap % 3 - 1;
        const bool av = (grow < 3136) && iy >= 0 && iy < 14 && ix >= 0 && ix < 14;
        const size_t rowoff = av ? ((size_t)(b * 196 + iy * 14 + ix)) * 4096 + ks * 2048 + wv * 16 : 0;
        baseH[rh] = av ? (const char*)rawh + rowoff : zpad;
        stp[rh] = av ? 64 : 0;
    }
    const char* gB = (const char*)Bh + (size_t)tap * 524288 + (size_t)ks * 32 * 8192 + lane * 16;

    int afo[4], bfo[4];
    #pragma unroll
    for (int i = 0; i < 4; ++i) afo[i] = quad * 2048 + (wm * 64 + i * 16 + lm) * 16;
    #pragma unroll
    for (int j = 0; j < 4; ++j) bfo[j] = 8192 + quad * 2048 + (wn * 64 + j * 16 + lm) * 16;

    floatx4 acc[4][4];
    const floatx4 fz = {0.f, 0.f, 0.f, 0.f};
    #pragma unroll
    for (int i = 0; i < 4; ++i)
        #pragma unroll
        for (int j = 0; j < 4; ++j) acc[i][j] = fz;

    for (int s = 0; s < 32; ++s) {
        glds16(baseH[0] + s * stp[0], L + wv * 2048);
        glds16(baseH[1] + s * stp[1], L + wv * 2048 + 1024);
        glds16(gB + (size_t)s * 8192 + (2 * wv) * 1024,     L + 8192 + (2 * wv) * 1024);
        glds16(gB + (size_t)s * 8192 + (2 * wv + 1) * 1024, L + 8192 + (2 * wv + 1) * 1024);
        __syncthreads();
        half8 ah[4], bh[4];
        #pragma unroll
        for (int i = 0; i < 4; ++i) ah[i] = *(const half8*)(L + afo[i]);
        #pragma unroll
        for (int j = 0; j < 4; ++j) bh[j] = *(const half8*)(L + bfo[j]);
        #pragma unroll
        for (int i = 0; i < 4; ++i)
            #pragma unroll
            for (int j = 0; j < 4; ++j)
                acc[i][j] = __builtin_amdgcn_mfma_f32_16x16x32_f16(ah[i], bh[j], acc[i][j], 0, 0, 0);
        __syncthreads();
    }
    #pragma unroll
    for (int i = 0; i < 4; ++i) {
        const int m0 = mt * 128 + wm * 64 + i * 16 + quad * 4;
        #pragma unroll
        for (int j = 0; j < 4; ++j) {
            const int n = wn * 64 + j * 16 + lm;
            #pragma unroll
            for (int r = 0; r < 4; ++r) {
                const int mm = m0 + r;
                if (mm < 3136)
                    y1p[((size_t)tx * 3136 + mm) * 128 + n] = acc[i][j][r];
            }
        }
    }
}

// ========= y1 reduce (18 slices) + bias + relu, fused with raw_mean (512-block partials) =====
__global__ __launch_bounds__(256)
void y1r_rm(const float* __restrict__ y1p, const float* __restrict__ bias,
            float* __restrict__ y1,
            const half_t* __restrict__ rh, float* __restrict__ concat)
{
    if (blockIdx.x < 1568) {
        const int t = blockIdx.x * 256 + threadIdx.x;
        const int n = t & 127;
        float s = bias[n];
        #pragma unroll
        for (int ks = 0; ks < 18; ++ks) s += y1p[(size_t)ks * 3136 * 128 + t];
        y1[t] = fmaxf(s, 0.f);
    } else {
        const int t = (blockIdx.x - 1568) * 256 + threadIdx.x;  // [0, 131072)
        const int n = t & 2047, b = (t >> 11) & 15, pc = t >> 15;
        float s = 0.f;
        const int p0 = pc * 49;
        for (int p = p0; p < p0 + 49; ++p)
            s += (float)rh[(size_t)(b * 196 + p) * 2048 + n];
        atomicAdd(concat + (size_t)b * 10240 + 8192 + n, s * (1.f / 196.f));
    }
}

// ================= tidy_all: all 3 score levels in one launch =================
__global__ __launch_bounds__(256)
void tidy_all(const float* __restrict__ y1, const float* __restrict__ y2,
              const float* __restrict__ y3,
              const float* __restrict__ w1, const float* __restrict__ b1,
              const float* __restrict__ w2, const float* __restrict__ b2,
              const float* __restrict__ w3, const float* __restrict__ b3,
              float* __restrict__ scores)
{
    const int wid = (blockIdx.x * 256 + threadIdx.x) >> 6;
    const int lane = threadIdx.x & 63;
    if (wid >= 16 * 1614) return;
    const int b = wid / 1614, idx = wid % 1614;
    const float* in; const float* w; const float* bi; int ch;
    if (idx < 1176) {
        ch = idx / 196; in = y1 + (size_t)(b * 196 + idx % 196) * 128; w = w1; bi = b1;
    } else if (idx < 1470) {
        const int i2 = idx - 1176;
        ch = i2 / 49; in = y2 + (size_t)(b * 49 + i2 % 49) * 128; w = w2; bi = b2;
    } else {
        const int i3 = idx - 1470;
        ch = i3 / 16; in = y3 + (size_t)(b * 16 + i3 % 16) * 128; w = w3; bi = b3;
    }
    const float* wr = w + ch * 128;
    float acc = in[lane] * wr[lane] + in[lane + 64] * wr[lane + 64];
    #pragma unroll
    for (int s = 32; s > 0; s >>= 1) acc += __shfl_down(acc, s, 64);
    if (lane == 0) scores[b * 1614 + idx] = acc + bi[ch];
}

// ================= 3x3 stride-2 conv, wt layout [tap][ic][oc] =================
__global__ __launch_bounds__(256)
void conv_s2(const float* __restrict__ in, const float* __restrict__ wt,
             const float* __restrict__ bias, float* __restrict__ out,
             int Win, int Wout)
{
    const int t = blockIdx.x * 256 + threadIdx.x;
    const int oc = t & 127;
    const int pos = (t >> 7) % (Wout * Wout);
    const int b = t / (128 * Wout * Wout);
    if (b >= 16) return;
    const int oy = pos / Wout, ox = pos % Wout;
    float acc = bias[oc];
    for (int dy = 0; dy < 3; ++dy) {
        const int y = oy * 2 + dy - 1;
        if (y < 0 || y >= Win) continue;
        for (int dx = 0; dx < 3; ++dx) {
            const int x = ox * 2 + dx - 1;
            if (x < 0 || x >= Win) continue;
            const float* ip = in + (size_t)(b * Win * Win + y * Win + x) * 128;
            const float* wp = wt + (size_t)(dy * 3 + dx) * 16384 + oc;
            for (int ic = 0; ic < 128; ++ic)
                acc += ip[ic] * wp[ic * 128];
        }
    }
    out[(size_t)(b * Wout * Wout + pos) * 128 + oc] = fmaxf(acc, 0.f);
}

// ================= NMS: register-resident scores/coords, 2 barriers per round =================
__global__ __launch_bounds__(256)
void nms(const float* __restrict__ scores, const int* __restrict__ anchors,
         int* __restrict__ top_idx)
{
    __shared__ float wv_v[4];
    __shared__ int wv_i[4];
    __shared__ int s_pick;
    const int b = blockIdx.x, tid = threadIdx.x;
    const int lane = tid & 63, wv = tid >> 6;
    float sc[7], ay0[7], ax0[7], ay1[7], ax1[7];
    unsigned int vmask = 0;
    #pragma unroll
    for (int j = 0; j < 7; ++j) {
        const int i = tid + j * 256;
        if (i < 1614) {
            sc[j]  = scores[b * 1614 + i];
            ay0[j] = (float)anchors[i * 4 + 0];
            ax0[j] = (float)anchors[i * 4 + 1];
            ay1[j] = (float)anchors[i * 4 + 2];
            ax1[j] = (float)anchors[i * 4 + 3];
            vmask |= 1u << j;
        }
    }
    for (int r = 0; r < 4; ++r) {
        float bv = -INFINITY; int bi = 0x7fffffff;
        #pragma unroll
        for (int j = 0; j < 7; ++j) {
            if (vmask & (1u << j)) {
                const float v = sc[j];
                const int i = tid + j * 256;
                if (v > bv || (v == bv && i < bi)) { bv = v; bi = i; }
            }
        }
        #pragma unroll
        for (int s = 32; s > 0; s >>= 1) {
            const float v2 = __shfl_down(bv, s, 64);
            const int   i2 = __shfl_down(bi, s, 64);
            if (v2 > bv || (v2 == bv && i2 < bi)) { bv = v2; bi = i2; }
        }
        if (lane == 0) { wv_v[wv] = bv; wv_i[wv] = bi; }
        __syncthreads();
        if (tid == 0) {
            float fv = wv_v[0]; int fi = wv_i[0];
            #pragma unroll
            for (int k = 1; k < 4; ++k)
                if (wv_v[k] > fv || (wv_v[k] == fv && wv_i[k] < fi)) { fv = wv_v[k]; fi = wv_i[k]; }
            s_pick = fi;
            top_idx[b * 4 + r] = fi;
        }
        __syncthreads();
        const int pick = s_pick;
        const float py0 = (float)anchors[pick * 4 + 0], px0 = (float)anchors[pick * 4 + 1];
        const float py1 = (float)anchors[pick * 4 + 2], px1 = (float)anchors[pick * 4 + 3];
        const float pa = (py1 - py0) * (px1 - px0);
        #pragma unroll
        for (int j = 0; j < 7; ++j) {
            if (vmask & (1u << j)) {
                const float ih = fminf(ay1[j], py1) - fmaxf(ay0[j], py0);
                const float iw = fminf(ax1[j], px1) - fmaxf(ax0[j], px0);
                const float inter = (ih < 0.f || iw < 0.f) ? 0.f : ih * iw;
                const float area = (ay1[j] - ay0[j]) * (ax1[j] - ax0[j]);
                const float iou = inter / ((area + pa) - inter);
                if (iou >= 0.25f) vmask &= ~(1u << j);
            }
        }
    }
}

// ================= crop_mean: mean over 49 positions of patchified crop ================
__global__ __launch_bounds__(256)
void crop_mean(const float* __restrict__ x, const int* __restrict__ anchors,
               const int* __restrict__ top_idx, float* __restrict__ abar)
{
    __shared__ float red[256];
    const int bi = blockIdx.x;               // 6144
    const int q = bi / 96, rem = bi % 96, c = rem >> 5, r = rem & 31;
    const int tid = threadIdx.x;
    const int cc = tid & 31, ps = tid >> 5;
    const int idx = top_idx[q];
    const int y0 = anchors[idx * 4 + 0], x0 = anchors[idx * 4 + 1];
    const int y1 = anchors[idx * 4 + 2], x1 = anchors[idx * 4 + 3];
    const float hh = (float)(y1 - y0), ww = (float)(x1 - x0);
    const float* xb = x + (size_t)((q >> 2) * 3 + c) * 200704;
    float acc = 0.f;
    for (int p = ps; p < 49; p += 8) {
        const int oy = p / 7, ox = p % 7;
        const int typ = oy * 32 + r;
        const int txp = ox * 32 + cc;
        const float sy = (float)typ * (hh - 1.0f) / 223.0f;
        const float fy = floorf(sy);
        const float wy = sy - fy;
        const int iy0 = y0 + (int)fy;
        const int iy1 = min(iy0 + 1, y1 - 1);
        const float sx = (float)txp * (ww - 1.0f) / 223.0f;
        const float fx = floorf(sx);
        const float wx = sx - fx;
        const int ix0 = x0 + (int)fx;
        const int ix1 = min(ix0 + 1, x1 - 1);
        const int ry0 = iy0 - 224, ry1 = iy1 - 224;
        const int rx0 = ix0 - 224, rx1 = ix1 - 224;
        const bool vy0 = (ry0 >= 0 && ry0 < 448), vy1 = (ry1 >= 0 && ry1 < 448);
        const bool vx0 = (rx0 >= 0 && rx0 < 448), vx1 = (rx1 >= 0 && rx1 < 448);
        const float v00 = (vy0 && vx0) ? xb[(size_t)ry0 * 448 + rx0] : 0.f;
        const float v01 = (vy0 && vx1) ? xb[(size_t)ry0 * 448 + rx1] : 0.f;
        const float v10 = (vy1 && vx0) ? xb[(size_t)ry1 * 448 + rx0] : 0.f;
        const float v11 = (vy1 && vx1) ? xb[(size_t)ry1 * 448 + rx1] : 0.f;
        const float top = v00 * (1.f - wx) + v01 * wx;
        const float bot = v10 * (1.f - wx) + v11 * wx;
        acc += top * (1.f - wy) + bot * wy;
    }
    red[tid] = acc;
    __syncthreads();
    if (tid < 32) {
        float s = 0.f;
        #pragma unroll
        for (int k = 0; k < 8; ++k) s += red[tid + 32 * k];
        abar[(size_t)q * 3072 + c * 1024 + r * 32 + cc] = s * (1.f / 49.f);
    }
}

// ================= part_gemm: Abar(64x3072) x bbwh, grid (32 nt, 8 ks), atomic into concat ==
__global__ __launch_bounds__(256)
void part_gemm(const float* __restrict__ abar, const half_t* __restrict__ Bh,
               float* __restrict__ concat)
{
    __shared__ __align__(16) char L[12288]; // Ah 0 (4096), Al 4096, B 8192 (4096)
    const int tid = threadIdx.x, lane = tid & 63, wv = tid >> 6;
    const int lm = lane & 15, quad = lane >> 4;
    const int nt = blockIdx.x, ks = blockIdx.y;
    const char* gBh = (const char*)Bh + ((size_t)nt * 96 + ks * 12) * 4096 + lane * 16;
    const int am = tid & 63, akg = tid >> 6;

    floatx4 acc[4], accl[4];
    const floatx4 fz = {0.f, 0.f, 0.f, 0.f};
    #pragma unroll
    for (int j = 0; j < 4; ++j) { acc[j] = fz; accl[j] = fz; }

    for (int s = 0; s < 12; ++s) {
        {
            const float* pa = abar + (size_t)am * 3072 + (ks * 12 + s) * 32 + akg * 8;
            float f[8];
            *(float4*)&f[0] = *(const float4*)pa;
            *(float4*)&f[4] = *(const float4*)(pa + 4);
            half8 h, l;
            #pragma unroll
            for (int j = 0; j < 8; ++j) {
                const half_t hh = (half_t)f[j];
                h[j] = hh;
                l[j] = (half_t)(f[j] - (float)hh);
            }
            *(half8*)(L + (akg * 64 + am) * 16) = h;
            *(half8*)(L + 4096 + (akg * 64 + am) * 16) = l;
        }
        glds16(gBh + (size_t)s * 4096 + wv * 1024, L + 8192 + wv * 1024);
        __syncthreads();
        half8 ah, al, bh[4];
        ah = *(const half8*)(L + (quad * 64 + wv * 16 + lm) * 16);
        al = *(const half8*)(L + 4096 + (quad * 64 + wv * 16 + lm) * 16);
        #pragma unroll
        for (int j = 0; j < 4; ++j) bh[j] = *(const half8*)(L + 8192 + (quad * 64 + j * 16 + lm) * 16);
        #pragma unroll
        for (int j = 0; j < 4; ++j) {
            acc[j]  = __builtin_amdgcn_mfma_f32_16x16x32_f16(ah, bh[j], acc[j], 0, 0, 0);
            accl[j] = __builtin_amdgcn_mfma_f32_16x16x32_f16(al, bh[j], accl[j], 0, 0, 0);
        }
        __syncthreads();
    }
    #pragma unroll
    for (int j = 0; j < 4; ++j) {
        const int n = nt * 64 + j * 16 + lm;
        #pragma unroll
        for (int r = 0; r < 4; ++r) {
            const int m = wv * 16 + quad * 4 + r;
            atomicAdd(concat + (size_t)(m >> 2) * 10240 + (m & 3) * 2048 + n,
                      acc[j][r] + accl[j][r]);
        }
    }
}

// ================= classifier GEMM: 25 n-chunks x 32 k-splits, LDS-tiled =================
__global__ __launch_bounds__(256)
void cls_gemm(const float* __restrict__ concat, const float* __restrict__ w,
              float* __restrict__ out)
{
    __shared__ float ws_[8 * 321];
    __shared__ float cs_[16 * 321];
    __shared__ float red[256];
    const int nchunk = blockIdx.x, ks = blockIdx.y;
    const int tid = threadIdx.x;
    for (int i = tid; i < 2560; i += 256) {
        const int r = i / 320, k = i % 320;
        ws_[r * 321 + k] = w[(size_t)(nchunk * 8 + r) * 10240 + ks * 320 + k];
    }
    for (int i = tid; i < 5120; i += 256) {
        const int r = i / 320, k = i % 320;
        cs_[r * 321 + k] = concat[(size_t)r * 10240 + ks * 320 + k];
    }
    __syncthreads();
    const int b = tid & 15, c = (tid >> 4) & 7, hf = tid >> 7;
    const float* cp = cs_ + b * 321 + hf * 160;
    const float* wp = ws_ + c * 321 + hf * 160;
    float a = 0.f;
    #pragma unroll 8
    for (int k = 0; k < 160; ++k) a += cp[k] * wp[k];
    red[tid] = a;
    __syncthreads();
    if (tid < 128) atomicAdd(out + b * 200 + nchunk * 8 + c, red[tid] + red[tid + 128]);
}

extern "C" void kernel_launch(void* const* d_in, const int* in_sizes, int n_in,
                              void* d_out, int out_size, void* d_ws, size_t ws_size,
                              hipStream_t stream)
{
    const float* x     = (const float*)d_in[0];
    const float* bb_w  = (const float*)d_in[1];
    const float* bb_b  = (const float*)d_in[2];
    const float* n1_dw = (const float*)d_in[3];
    const float* n1_db = (const float*)d_in[4];
    const float* n1_tw = (const float*)d_in[5];
    const float* n1_tb = (const float*)d_in[6];
    const float* n2_dw = (const float*)d_in[7];
    const float* n2_db = (const float*)d_in[8];
    const float* n2_tw = (const float*)d_in[9];
    const float* n2_tb = (const float*)d_in[10];
    const float* n3_dw = (const float*)d_in[11];
    const float* n3_db = (const float*)d_in[12];
    const float* n3_tw = (const float*)d_in[13];
    const float* n3_tb = (const float*)d_in[14];
    const float* cn_w  = (const float*)d_in[15];
    const float* cn_b  = (const float*)d_in[16];
    const int*   anchors = (const int*)d_in[17];
    float* out = (float*)d_out;
    char* W = (char*)d_ws;

    half_t* bbwh  = (half_t*)(W + 0);
    float*  zpad  = (float*)(W + 12582912);
    int*    topidx= (int*)(W + 12583936);
    float*  scores= (float*)(W + 12584960);
    float*  y1    = (float*)(W + 12688384);
    float*  y2    = (float*)(W + 14294016);
    float*  y3    = (float*)(W + 14695424);
    float*  concat= (float*)(W + 14826496);
    half_t* w1h   = (half_t*)(W + 15481856);
    float*  wt2t  = (float*)(W + 20200448);
    float*  wt3t  = (float*)(W + 20790272);
    char* E = W + 21380096;
    half_t* xh    = (half_t*)E;
    float*  y1p   = (float*)E;      // alias: xh dead after gemm_x
    char* F = W + 60701696;
    half_t* rawh  = (half_t*)F;
    float*  abar  = (float*)F;      // alias: raw dead after gemm_nav + y1r_rm

    prep_all<<<9806, 256, 0, stream>>>(x, bb_w, n1_dw, n2_dw, n3_dw, cn_b, bb_b,
                                       xh, bbwh, w1h, wt2t, wt3t, out, zpad, concat);

    gemm_x<<<dim3(16, 25), 256, 0, stream>>>(xh, bbwh, bb_b, rawh);
    gemm_nav<<<dim3(18, 25), 256, 0, stream>>>(rawh, w1h, (const char*)zpad, y1p);
    y1r_rm<<<2080, 256, 0, stream>>>(y1p, n1_db, y1, rawh, concat);

    conv_s2<<<392, 256, 0, stream>>>(y1, wt2t, n2_db, y2, 14, 7);
    conv_s2<<<128, 256, 0, stream>>>(y2, wt3t, n3_db, y3, 7, 4);
    tidy_all<<<6456, 256, 0, stream>>>(y1, y2, y3, n1_tw, n1_tb, n2_tw, n2_tb,
                                       n3_tw, n3_tb, scores);

    nms<<<16, 256, 0, stream>>>(scores, anchors, topidx);
    crop_mean<<<6144, 256, 0, stream>>>(x, anchors, topidx, abar);

    part_gemm<<<dim3(32, 8), 256, 0, stream>>>(abar, bbwh, concat);
    cls_gemm<<<dim3(25, 32), 256, 0, stream>>>(concat, cn_w, out);
}

// Round 12
// 393.707 us; speedup vs baseline: 1.1887x; 1.0404x over previous
//
#include <hip/hip_runtime.h>
#include <cstdint>
#include <math.h>

typedef _Float16 half_t;
typedef __attribute__((ext_vector_type(8))) _Float16 half8;
typedef __attribute__((ext_vector_type(4))) float floatx4;

// ---------------- workspace byte layout ----------------
// bbwh   @ 0            12,582,912   fp16 [32 nt][96 s][4 kg][64 n][16B]
// zpad   @ 12,582,912   1,024
// topidx @ 12,583,936   1,024
// scores @ 12,584,960   103,424
// y1     @ 12,688,384   1,605,632
// y2     @ 14,294,016   401,408
// y3     @ 14,695,424   131,072
// concat @ 14,826,496   655,360      (part rows bias-seeded, raw rows 0-seeded; atomics add)
// w1h    @ 15,481,856   4,718,592    fp16 [9 tap][64 s][4 kg][128 n][16B]
// wt2t   @ 20,200,448   589,824
// wt3t   @ 20,790,272   589,824
// E      @ 21,380,096   39,321,600:  phase1 xh(19,660,800)
//                                    phase2 y1p 18 slices (28,901,376)
// F      @ 60,701,696:  phase1 rawh(12,845,056) fp16 single
//                       phase2 abar(786,432) fp32
// end 86,391,808

typedef __attribute__((address_space(3))) unsigned int lds_u32;
typedef const __attribute__((address_space(1))) unsigned int glb_u32;
__device__ __forceinline__ void glds16(const void* g, void* l) {
    __builtin_amdgcn_global_load_lds((glb_u32*)g, (lds_u32*)l, 16, 0, 0);
}

// ================= prep_all =================
__global__ __launch_bounds__(256)
void prep_all(const float* __restrict__ x, const float* __restrict__ bbw,
              const float* __restrict__ n1dw, const float* __restrict__ n2dw,
              const float* __restrict__ n3dw, const float* __restrict__ cnb,
              const float* __restrict__ bbb,
              half_t* __restrict__ xh,
              half_t* __restrict__ bh, half_t* __restrict__ w1h,
              float* __restrict__ wt2t, float* __restrict__ wt3t,
              float* __restrict__ out, float* __restrict__ zpad,
              float* __restrict__ concat)
{
    const long t = (long)blockIdx.x * 256 + threadIdx.x;
    if (t < 1228800) {
        const int m = (int)(t % 3200), k8 = (int)(t / 3200);
        const int mt = m >> 7, mr = m & 127, s = k8 >> 2, kg = k8 & 3;
        const size_t dst = (((size_t)(mt * 96 + s) * 4 + kg) * 128 + mr) * 8;
        float f[8];
        if (m < 3136) {
            const int bq = m / 196, pos = m % 196, oy = pos / 14, ox = pos % 14;
            const int k = k8 * 8, c = k >> 10, r = (k >> 5) & 31, cc = k & 31;
            const float* p = x + ((size_t)(bq * 3 + c) * 448 + oy * 32 + r) * 448 + ox * 32 + cc;
            *(float4*)&f[0] = *(const float4*)p;
            *(float4*)&f[4] = *(const float4*)(p + 4);
        } else {
            #pragma unroll
            for (int j = 0; j < 8; ++j) f[j] = 0.f;
        }
        half8 h;
        #pragma unroll
        for (int j = 0; j < 8; ++j) h[j] = (half_t)f[j];
        *(half8*)(xh + dst) = h;
    } else if (t < 2015232) {
        const int t2 = (int)(t - 1228800);
        const int n = t2 / 384, k8 = t2 % 384;
        const float* p = bbw + (size_t)n * 3072 + k8 * 8;
        float f[8];
        *(float4*)&f[0] = *(const float4*)p;
        *(float4*)&f[4] = *(const float4*)(p + 4);
        const int nt = n >> 6, nr = n & 63, s = k8 >> 2, kg = k8 & 3;
        const size_t dst = (((size_t)(nt * 96 + s) * 4 + kg) * 64 + nr) * 8;
        half8 h;
        #pragma unroll
        for (int j = 0; j < 8; ++j) h[j] = (half_t)f[j];
        *(half8*)(bh + dst) = h;
    } else if (t < 2048000) {
        const int t2 = (int)(t - 2015232);
        const int n = t2 >> 8, ic8 = t2 & 255;
        const int s = ic8 >> 2, kg = ic8 & 3;
        const float* src = n1dw + ((size_t)n * 2048 + ic8 * 8) * 9;
        float buf[72];
        #pragma unroll
        for (int i = 0; i < 18; ++i) *(float4*)&buf[i * 4] = *(const float4*)(src + i * 4);
        #pragma unroll
        for (int tap = 0; tap < 9; ++tap) {
            half8 h;
            #pragma unroll
            for (int j = 0; j < 8; ++j) h[j] = (half_t)buf[j * 9 + tap];
            const size_t dst = (((size_t)(tap * 64 + s) * 4 + kg) * 128 + n) * 8;
            *(half8*)(w1h + dst) = h;
        }
    } else if (t < 2195456) {
        const int t2 = (int)(t - 2048000);
        const int oc = t2 % 128, rest = t2 / 128, ic = rest % 128, tap = rest / 128;
        wt2t[(tap * 128 + ic) * 128 + oc] = n2dw[((size_t)oc * 128 + ic) * 9 + tap];
    } else if (t < 2342912) {
        const int t2 = (int)(t - 2195456);
        const int oc = t2 % 128, rest = t2 / 128, ic = rest % 128, tap = rest / 128;
        wt3t[(tap * 128 + ic) * 128 + oc] = n3dw[((size_t)oc * 128 + ic) * 9 + tap];
    } else if (t < 2346112) {
        const int i = (int)(t - 2342912);
        out[i] = cnb[i % 200];
    } else if (t < 2346368) {
        zpad[t - 2346112] = 0.f;
    } else if (t < 2510208) {
        const int i = (int)(t - 2346368);
        const int r = i % 10240;
        concat[i] = (r < 8192) ? bbb[r & 2047] : 0.f;
    }
}

// ====== gemm_x: fp16 single-product 64Mx128N, BK=64, grid (16 nt, 49 mt) ======
__global__ __launch_bounds__(256)
void gemm_x(const half_t* __restrict__ Ah, const half_t* __restrict__ Bh,
            const float* __restrict__ bias, half_t* __restrict__ outh)
{
    __shared__ __align__(16) char L[24576]; // A [2 ki][4 kg][64 m][16B] = 8KB; B @8192 [2ki][2nh][4kg][64n][16B] = 16KB
    const int tid = threadIdx.x, lane = tid & 63, wv = tid >> 6;
    const int nt = blockIdx.x, mt = blockIdx.y;   // 16 x 49
    const int lm = lane & 15, quad = lane >> 4;

    const char* gA = (const char*)Ah + (size_t)(mt >> 1) * 786432 + (mt & 1) * 1024 + lane * 16;
    const char* gB = (const char*)Bh + (size_t)(2 * nt) * 393216 + lane * 16;

    // staging: wave wv -> A chunks {2wv,2wv+1}: sIter=a>>2, kg=a&3; B chunks sIter=wv>>1, nh=wv&1, kg=0..3
    const int a0 = 2 * wv, a1 = 2 * wv + 1;
    const int aof0 = (a0 >> 2) * 4096 + (a0 & 3) * 1024;
    const int aog0 = (a0 >> 2) * 8192 + (a0 & 3) * 2048;
    const int aof1 = (a1 >> 2) * 4096 + (a1 & 3) * 1024;
    const int aog1 = (a1 >> 2) * 8192 + (a1 & 3) * 2048;
    const int bsi = wv >> 1, bnh = wv & 1;
    const size_t bgb = (size_t)bnh * 393216 + bsi * 4096;
    const int blb = 8192 + (bsi * 2 + bnh) * 4096;

    floatx4 acc[8];
    const floatx4 fz = {0.f, 0.f, 0.f, 0.f};
    #pragma unroll
    for (int j = 0; j < 8; ++j) acc[j] = fz;

    for (int s = 0; s < 48; ++s) {
        const size_t sa = (size_t)(2 * s) * 8192;
        const size_t sb = (size_t)(2 * s) * 4096;
        glds16(gA + sa + aog0, L + aof0);
        glds16(gA + sa + aog1, L + aof1);
        #pragma unroll
        for (int i = 0; i < 4; ++i)
            glds16(gB + bgb + sb + i * 1024, L + blb + i * 1024);
        __syncthreads();
        #pragma unroll
        for (int ki = 0; ki < 2; ++ki) {
            half8 a = *(const half8*)(L + ki * 4096 + quad * 1024 + (wv * 16 + lm) * 16);
            #pragma unroll
            for (int j = 0; j < 8; ++j) {
                half8 b = *(const half8*)(L + 8192 + (ki * 2 + (j >> 2)) * 4096 + quad * 1024 + ((j & 3) * 16 + lm) * 16);
                acc[j] = __builtin_amdgcn_mfma_f32_16x16x32_f16(a, b, acc[j], 0, 0, 0);
            }
        }
        __syncthreads();
    }
    const int m0 = mt * 64 + wv * 16 + quad * 4;
    #pragma unroll
    for (int j = 0; j < 8; ++j) {
        const int n = nt * 128 + j * 16 + lm;
        const float bv = bias[n];
        #pragma unroll
        for (int r = 0; r < 4; ++r)
            outh[(size_t)(m0 + r) * 2048 + n] = (half_t)(acc[j][r] + bv);
    }
}

// ====== gemm_nav: fp16 single-product 64Mx128N, BK=64, grid (18 tx, 49 mt) ======
__global__ __launch_bounds__(256)
void gemm_nav(const half_t* __restrict__ rawh, const half_t* __restrict__ Bh,
              const char* __restrict__ zpad, float* __restrict__ y1p)
{
    __shared__ __align__(16) char L[24576]; // A [2ki][4kg][64 rows][16B]=8KB; B @8192 [2 sIter][4 kg][128 n][16B]=16KB
    const int tid = threadIdx.x, lane = tid & 63, wv = tid >> 6;
    const int tx = blockIdx.x;   // tap = tx>>1, ks = tx&1
    const int tap = tx >> 1, ks = tx & 1;
    const int mt = blockIdx.y;   // 49
    const int lm = lane & 15, quad = lane >> 4;

    // per-lane A row pointer (halo -> zpad)
    const int grow = mt * 64 + lane;
    const int b = grow / 196, pos = grow % 196, oy = pos / 14, ox = pos % 14;
    const int iy = oy + tap / 3 - 1, ix = ox + tap % 3 - 1;
    const bool av = (iy >= 0 && iy < 14 && ix >= 0 && ix < 14);
    const char* abase = av ? (const char*)rawh + ((size_t)(b * 196 + iy * 14 + ix)) * 4096 + ks * 2048 : zpad;
    const int stp = av ? 1 : 0;

    // A chunks {2wv, 2wv+1}: i: ki=i>>2, kg=i&3 -> row-byte off ki*64+kg*16, LDS ki*4096+kg*1024
    const int a0 = 2 * wv, a1 = 2 * wv + 1;
    const int ac0 = (a0 >> 2) * 64 + (a0 & 3) * 16, al0 = (a0 >> 2) * 4096 + (a0 & 3) * 1024;
    const int ac1 = (a1 >> 2) * 64 + (a1 & 3) * 16, al1 = (a1 >> 2) * 4096 + (a1 & 3) * 1024;
    // B chunks: wave wv -> sIter=wv>>1, nh=wv&1, kg=0..3
    const int bsi = wv >> 1, bnh = wv & 1;
    const char* gB = (const char*)Bh + (size_t)tap * 524288 + (size_t)(ks * 32) * 8192 + bnh * 1024 + lane * 16;
    const int blb = 8192 + bsi * 8192 + bnh * 1024;

    floatx4 acc[8];
    const floatx4 fz = {0.f, 0.f, 0.f, 0.f};
    #pragma unroll
    for (int j = 0; j < 8; ++j) acc[j] = fz;

    for (int s = 0; s < 16; ++s) {
        const int rowo = s * 128;
        glds16(abase + stp * (rowo + ac0), L + al0);
        glds16(abase + stp * (rowo + ac1), L + al1);
        const size_t sb = (size_t)(2 * s + bsi) * 8192;
        #pragma unroll
        for (int i = 0; i < 4; ++i)
            glds16(gB + sb + i * 2048, L + blb + i * 2048);
        __syncthreads();
        #pragma unroll
        for (int ki = 0; ki < 2; ++ki) {
            half8 a = *(const half8*)(L + ki * 4096 + quad * 1024 + (wv * 16 + lm) * 16);
            #pragma unroll
            for (int j = 0; j < 8; ++j) {
                half8 bq = *(const half8*)(L + 8192 + ki * 8192 + quad * 2048 + (j * 16 + lm) * 16);
                acc[j] = __builtin_amdgcn_mfma_f32_16x16x32_f16(a, bq, acc[j], 0, 0, 0);
            }
        }
        __syncthreads();
    }
    const int m0 = mt * 64 + wv * 16 + quad * 4;
    #pragma unroll
    for (int j = 0; j < 8; ++j) {
        const int n = j * 16 + lm;
        #pragma unroll
        for (int r = 0; r < 4; ++r)
            y1p[((size_t)tx * 3136 + m0 + r) * 128 + n] = acc[j][r];
    }
}

// ========= y1 reduce (18 slices) + bias + relu, fused with raw_mean =========
__global__ __launch_bounds__(256)
void y1r_rm(const float* __restrict__ y1p, const float* __restrict__ bias,
            float* __restrict__ y1,
            const half_t* __restrict__ rh, float* __restrict__ concat)
{
    if (blockIdx.x < 1568) {
        const int t = blockIdx.x * 256 + threadIdx.x;
        const int n = t & 127;
        float s = bias[n];
        #pragma unroll
        for (int ks = 0; ks < 18; ++ks) s += y1p[(size_t)ks * 3136 * 128 + t];
        y1[t] = fmaxf(s, 0.f);
    } else {
        const int t = (blockIdx.x - 1568) * 256 + threadIdx.x;
        const int n = t & 2047, b = (t >> 11) & 15, pc = t >> 15;
        float s = 0.f;
        const int p0 = pc * 49;
        for (int p = p0; p < p0 + 49; ++p)
            s += (float)rh[(size_t)(b * 196 + p) * 2048 + n];
        atomicAdd(concat + (size_t)b * 10240 + 8192 + n, s * (1.f / 196.f));
    }
}

// ================= tidy helper (wave per output) =================
__device__ __forceinline__ void tidy_one(const float* in, const float* wr, float bi,
                                         float* dst, int lane)
{
    float acc = in[lane] * wr[lane] + in[lane + 64] * wr[lane + 64];
    #pragma unroll
    for (int s = 32; s > 0; s >>= 1) acc += __shfl_down(acc, s, 64);
    if (lane == 0) *dst = acc + bi;
}

// ================= conv_s2 body =================
__device__ __forceinline__ void conv_s2_body(int t, const float* __restrict__ in,
                                             const float* __restrict__ wt,
                                             const float* __restrict__ bias,
                                             float* __restrict__ out, int Win, int Wout)
{
    const int oc = t & 127;
    const int pos = (t >> 7) % (Wout * Wout);
    const int b = t / (128 * Wout * Wout);
    if (b >= 16) return;
    const int oy = pos / Wout, ox = pos % Wout;
    float acc = bias[oc];
    for (int dy = 0; dy < 3; ++dy) {
        const int y = oy * 2 + dy - 1;
        if (y < 0 || y >= Win) continue;
        for (int dx = 0; dx < 3; ++dx) {
            const int x = ox * 2 + dx - 1;
            if (x < 0 || x >= Win) continue;
            const float* ip = in + (size_t)(b * Win * Win + y * Win + x) * 128;
            const float* wp = wt + (size_t)(dy * 3 + dx) * 16384 + oc;
            for (int ic = 0; ic < 128; ++ic)
                acc += ip[ic] * wp[ic * 128];
        }
    }
    out[(size_t)(b * Wout * Wout + pos) * 128 + oc] = fmaxf(acc, 0.f);
}

// ============ fused: conv_s2 y1->y2 (blocks 0..391)  ||  tidy level-1 (392..5095) ============
__global__ __launch_bounds__(256)
void conv2_tidy1(const float* __restrict__ y1, const float* __restrict__ wt2t,
                 const float* __restrict__ b2d, float* __restrict__ y2,
                 const float* __restrict__ w1t, const float* __restrict__ b1t,
                 float* __restrict__ scores)
{
    if (blockIdx.x < 392) {
        conv_s2_body(blockIdx.x * 256 + threadIdx.x, y1, wt2t, b2d, y2, 14, 7);
    } else {
        const int wid = (blockIdx.x - 392) * 4 + (threadIdx.x >> 6);
        const int lane = threadIdx.x & 63;
        if (wid >= 16 * 1176) return;
        const int b = wid / 1176, i1 = wid % 1176;
        const int ch = i1 / 196, pos = i1 % 196;
        tidy_one(y1 + (size_t)(b * 196 + pos) * 128, w1t + ch * 128, b1t[ch],
                 scores + b * 1614 + i1, lane);
    }
}

// ============ fused: conv_s2 y2->y3 (blocks 0..127)  ||  tidy level-2 (128..1303) ============
__global__ __launch_bounds__(256)
void conv3_tidy2(const float* __restrict__ y2, const float* __restrict__ wt3t,
                 const float* __restrict__ b3d, float* __restrict__ y3,
                 const float* __restrict__ w2t, const float* __restrict__ b2t,
                 float* __restrict__ scores)
{
    if (blockIdx.x < 128) {
        conv_s2_body(blockIdx.x * 256 + threadIdx.x, y2, wt3t, b3d, y3, 7, 4);
    } else {
        const int wid = (blockIdx.x - 128) * 4 + (threadIdx.x >> 6);
        const int lane = threadIdx.x & 63;
        if (wid >= 16 * 294) return;
        const int b = wid / 294, i2 = wid % 294;
        const int ch = i2 / 49, pos = i2 % 49;
        tidy_one(y2 + (size_t)(b * 49 + pos) * 128, w2t + ch * 128, b2t[ch],
                 scores + b * 1614 + 1176 + i2, lane);
    }
}

// ================= tidy level-3 =================
__global__ __launch_bounds__(256)
void tidy3(const float* __restrict__ y3, const float* __restrict__ w3t,
           const float* __restrict__ b3t, float* __restrict__ scores)
{
    const int wid = blockIdx.x * 4 + (threadIdx.x >> 6);
    const int lane = threadIdx.x & 63;
    if (wid >= 16 * 144) return;
    const int b = wid / 144, i3 = wid % 144;
    const int ch = i3 / 16, pos = i3 % 16;
    tidy_one(y3 + (size_t)(b * 16 + pos) * 128, w3t + ch * 128, b3t[ch],
             scores + b * 1614 + 1470 + i3, lane);
}

// ================= NMS: register-resident, shuffle reduce =================
__global__ __launch_bounds__(256)
void nms(const float* __restrict__ scores, const int* __restrict__ anchors,
         int* __restrict__ top_idx)
{
    __shared__ float wv_v[4];
    __shared__ int wv_i[4];
    __shared__ int s_pick;
    const int b = blockIdx.x, tid = threadIdx.x;
    const int lane = tid & 63, wv = tid >> 6;
    float sc[7], ay0[7], ax0[7], ay1[7], ax1[7];
    unsigned int vmask = 0;
    #pragma unroll
    for (int j = 0; j < 7; ++j) {
        const int i = tid + j * 256;
        if (i < 1614) {
            sc[j]  = scores[b * 1614 + i];
            ay0[j] = (float)anchors[i * 4 + 0];
            ax0[j] = (float)anchors[i * 4 + 1];
            ay1[j] = (float)anchors[i * 4 + 2];
            ax1[j] = (float)anchors[i * 4 + 3];
            vmask |= 1u << j;
        }
    }
    for (int r = 0; r < 4; ++r) {
        float bv = -INFINITY; int bi = 0x7fffffff;
        #pragma unroll
        for (int j = 0; j < 7; ++j) {
            if (vmask & (1u << j)) {
                const float v = sc[j];
                const int i = tid + j * 256;
                if (v > bv || (v == bv && i < bi)) { bv = v; bi = i; }
            }
        }
        #pragma unroll
        for (int s = 32; s > 0; s >>= 1) {
            const float v2 = __shfl_down(bv, s, 64);
            const int   i2 = __shfl_down(bi, s, 64);
            if (v2 > bv || (v2 == bv && i2 < bi)) { bv = v2; bi = i2; }
        }
        if (lane == 0) { wv_v[wv] = bv; wv_i[wv] = bi; }
        __syncthreads();
        if (tid == 0) {
            float fv = wv_v[0]; int fi = wv_i[0];
            #pragma unroll
            for (int k = 1; k < 4; ++k)
                if (wv_v[k] > fv || (wv_v[k] == fv && wv_i[k] < fi)) { fv = wv_v[k]; fi = wv_i[k]; }
            s_pick = fi;
            top_idx[b * 4 + r] = fi;
        }
        __syncthreads();
        const int pick = s_pick;
        const float py0 = (float)anchors[pick * 4 + 0], px0 = (float)anchors[pick * 4 + 1];
        const float py1 = (float)anchors[pick * 4 + 2], px1 = (float)anchors[pick * 4 + 3];
        const float pa = (py1 - py0) * (px1 - px0);
        #pragma unroll
        for (int j = 0; j < 7; ++j) {
            if (vmask & (1u << j)) {
                const float ih = fminf(ay1[j], py1) - fmaxf(ay0[j], py0);
                const float iw = fminf(ax1[j], px1) - fmaxf(ax0[j], px0);
                const float inter = (ih < 0.f || iw < 0.f) ? 0.f : ih * iw;
                const float area = (ay1[j] - ay0[j]) * (ax1[j] - ax0[j]);
                const float iou = inter / ((area + pa) - inter);
                if (iou >= 0.25f) vmask &= ~(1u << j);
            }
        }
    }
}

// ================= crop_mean =================
__global__ __launch_bounds__(256)
void crop_mean(const float* __restrict__ x, const int* __restrict__ anchors,
               const int* __restrict__ top_idx, float* __restrict__ abar)
{
    __shared__ float red[256];
    const int bi = blockIdx.x;               // 6144
    const int q = bi / 96, rem = bi % 96, c = rem >> 5, r = rem & 31;
    const int tid = threadIdx.x;
    const int cc = tid & 31, ps = tid >> 5;
    const int idx = top_idx[q];
    const int y0 = anchors[idx * 4 + 0], x0 = anchors[idx * 4 + 1];
    const int y1 = anchors[idx * 4 + 2], x1 = anchors[idx * 4 + 3];
    const float hh = (float)(y1 - y0), ww = (float)(x1 - x0);
    const float* xb = x + (size_t)((q >> 2) * 3 + c) * 200704;
    float acc = 0.f;
    for (int p = ps; p < 49; p += 8) {
        const int oy = p / 7, ox = p % 7;
        const int typ = oy * 32 + r;
        const int txp = ox * 32 + cc;
        const float sy = (float)typ * (hh - 1.0f) / 223.0f;
        const float fy = floorf(sy);
        const float wy = sy - fy;
        const int iy0 = y0 + (int)fy;
        const int iy1 = min(iy0 + 1, y1 - 1);
        const float sx = (float)txp * (ww - 1.0f) / 223.0f;
        const float fx = floorf(sx);
        const float wx = sx - fx;
        const int ix0 = x0 + (int)fx;
        const int ix1 = min(ix0 + 1, x1 - 1);
        const int ry0 = iy0 - 224, ry1 = iy1 - 224;
        const int rx0 = ix0 - 224, rx1 = ix1 - 224;
        const bool vy0 = (ry0 >= 0 && ry0 < 448), vy1 = (ry1 >= 0 && ry1 < 448);
        const bool vx0 = (rx0 >= 0 && rx0 < 448), vx1 = (rx1 >= 0 && rx1 < 448);
        const float v00 = (vy0 && vx0) ? xb[(size_t)ry0 * 448 + rx0] : 0.f;
        const float v01 = (vy0 && vx1) ? xb[(size_t)ry0 * 448 + rx1] : 0.f;
        const float v10 = (vy1 && vx0) ? xb[(size_t)ry1 * 448 + rx0] : 0.f;
        const float v11 = (vy1 && vx1) ? xb[(size_t)ry1 * 448 + rx1] : 0.f;
        const float top = v00 * (1.f - wx) + v01 * wx;
        const float bot = v10 * (1.f - wx) + v11 * wx;
        acc += top * (1.f - wy) + bot * wy;
    }
    red[tid] = acc;
    __syncthreads();
    if (tid < 32) {
        float s = 0.f;
        #pragma unroll
        for (int k = 0; k < 8; ++k) s += red[tid + 32 * k];
        abar[(size_t)q * 3072 + c * 1024 + r * 32 + cc] = s * (1.f / 49.f);
    }
}

// ================= part_gemm =================
__global__ __launch_bounds__(256)
void part_gemm(const float* __restrict__ abar, const half_t* __restrict__ Bh,
               float* __restrict__ concat)
{
    __shared__ __align__(16) char L[12288];
    const int tid = threadIdx.x, lane = tid & 63, wv = tid >> 6;
    const int lm = lane & 15, quad = lane >> 4;
    const int nt = blockIdx.x, ks = blockIdx.y;
    const char* gBh = (const char*)Bh + ((size_t)nt * 96 + ks * 12) * 4096 + lane * 16;
    const int am = tid & 63, akg = tid >> 6;

    floatx4 acc[4], accl[4];
    const floatx4 fz = {0.f, 0.f, 0.f, 0.f};
    #pragma unroll
    for (int j = 0; j < 4; ++j) { acc[j] = fz; accl[j] = fz; }

    for (int s = 0; s < 12; ++s) {
        {
            const float* pa = abar + (size_t)am * 3072 + (ks * 12 + s) * 32 + akg * 8;
            float f[8];
            *(float4*)&f[0] = *(const float4*)pa;
            *(float4*)&f[4] = *(const float4*)(pa + 4);
            half8 h, l;
            #pragma unroll
            for (int j = 0; j < 8; ++j) {
                const half_t hh = (half_t)f[j];
                h[j] = hh;
                l[j] = (half_t)(f[j] - (float)hh);
            }
            *(half8*)(L + (akg * 64 + am) * 16) = h;
            *(half8*)(L + 4096 + (akg * 64 + am) * 16) = l;
        }
        glds16(gBh + (size_t)s * 4096 + wv * 1024, L + 8192 + wv * 1024);
        __syncthreads();
        half8 ah, al, bh[4];
        ah = *(const half8*)(L + (quad * 64 + wv * 16 + lm) * 16);
        al = *(const half8*)(L + 4096 + (quad * 64 + wv * 16 + lm) * 16);
        #pragma unroll
        for (int j = 0; j < 4; ++j) bh[j] = *(const half8*)(L + 8192 + (quad * 64 + j * 16 + lm) * 16);
        #pragma unroll
        for (int j = 0; j < 4; ++j) {
            acc[j]  = __builtin_amdgcn_mfma_f32_16x16x32_f16(ah, bh[j], acc[j], 0, 0, 0);
            accl[j] = __builtin_amdgcn_mfma_f32_16x16x32_f16(al, bh[j], accl[j], 0, 0, 0);
        }
        __syncthreads();
    }
    #pragma unroll
    for (int j = 0; j < 4; ++j) {
        const int n = nt * 64 + j * 16 + lm;
        #pragma unroll
        for (int r = 0; r < 4; ++r) {
            const int m = wv * 16 + quad * 4 + r;
            atomicAdd(concat + (size_t)(m >> 2) * 10240 + (m & 3) * 2048 + n,
                      acc[j][r] + accl[j][r]);
        }
    }
}

// ================= classifier GEMM =================
__global__ __launch_bounds__(256)
void cls_gemm(const float* __restrict__ concat, const float* __restrict__ w,
              float* __restrict__ out)
{
    __shared__ float ws_[8 * 321];
    __shared__ float cs_[16 * 321];
    __shared__ float red[256];
    const int nchunk = blockIdx.x, ks = blockIdx.y;
    const int tid = threadIdx.x;
    for (int i = tid; i < 2560; i += 256) {
        const int r = i / 320, k = i % 320;
        ws_[r * 321 + k] = w[(size_t)(nchunk * 8 + r) * 10240 + ks * 320 + k];
    }
    for (int i = tid; i < 5120; i += 256) {
        const int r = i / 320, k = i % 320;
        cs_[r * 321 + k] = concat[(size_t)r * 10240 + ks * 320 + k];
    }
    __syncthreads();
    const int b = tid & 15, c = (tid >> 4) & 7, hf = tid >> 7;
    const float* cp = cs_ + b * 321 + hf * 160;
    const float* wp = ws_ + c * 321 + hf * 160;
    float a = 0.f;
    #pragma unroll 8
    for (int k = 0; k < 160; ++k) a += cp[k] * wp[k];
    red[tid] = a;
    __syncthreads();
    if (tid < 128) atomicAdd(out + b * 200 + nchunk * 8 + c, red[tid] + red[tid + 128]);
}

extern "C" void kernel_launch(void* const* d_in, const int* in_sizes, int n_in,
                              void* d_out, int out_size, void* d_ws, size_t ws_size,
                              hipStream_t stream)
{
    const float* x     = (const float*)d_in[0];
    const float* bb_w  = (const float*)d_in[1];
    const float* bb_b  = (const float*)d_in[2];
    const float* n1_dw = (const float*)d_in[3];
    const float* n1_db = (const float*)d_in[4];
    const float* n1_tw = (const float*)d_in[5];
    const float* n1_tb = (const float*)d_in[6];
    const float* n2_dw = (const float*)d_in[7];
    const float* n2_db = (const float*)d_in[8];
    const float* n2_tw = (const float*)d_in[9];
    const float* n2_tb = (const float*)d_in[10];
    const float* n3_dw = (const float*)d_in[11];
    const float* n3_db = (const float*)d_in[12];
    const float* n3_tw = (const float*)d_in[13];
    const float* n3_tb = (const float*)d_in[14];
    const float* cn_w  = (const float*)d_in[15];
    const float* cn_b  = (const float*)d_in[16];
    const int*   anchors = (const int*)d_in[17];
    float* out = (float*)d_out;
    char* W = (char*)d_ws;

    half_t* bbwh  = (half_t*)(W + 0);
    float*  zpad  = (float*)(W + 12582912);
    int*    topidx= (int*)(W + 12583936);
    float*  scores= (float*)(W + 12584960);
    float*  y1    = (float*)(W + 12688384);
    float*  y2    = (float*)(W + 14294016);
    float*  y3    = (float*)(W + 14695424);
    float*  concat= (float*)(W + 14826496);
    half_t* w1h   = (half_t*)(W + 15481856);
    float*  wt2t  = (float*)(W + 20200448);
    float*  wt3t  = (float*)(W + 20790272);
    char* E = W + 21380096;
    half_t* xh    = (half_t*)E;
    float*  y1p   = (float*)E;      // alias: xh dead after gemm_x
    char* F = W + 60701696;
    half_t* rawh  = (half_t*)F;
    float*  abar  = (float*)F;      // alias: raw dead after gemm_nav + y1r_rm

    prep_all<<<9806, 256, 0, stream>>>(x, bb_w, n1_dw, n2_dw, n3_dw, cn_b, bb_b,
                                       xh, bbwh, w1h, wt2t, wt3t, out, zpad, concat);

    gemm_x<<<dim3(16, 49), 256, 0, stream>>>(xh, bbwh, bb_b, rawh);
    gemm_nav<<<dim3(18, 49), 256, 0, stream>>>(rawh, w1h, (const char*)zpad, y1p);
    y1r_rm<<<2080, 256, 0, stream>>>(y1p, n1_db, y1, rawh, concat);

    conv2_tidy1<<<5096, 256, 0, stream>>>(y1, wt2t, n2_db, y2, n1_tw, n1_tb, scores);
    conv3_tidy2<<<1304, 256, 0, stream>>>(y2, wt3t, n3_db, y3, n2_tw, n2_tb, scores);
    tidy3<<<576, 256, 0, stream>>>(y3, n3_tw, n3_tb, scores);

    nms<<<16, 256, 0, stream>>>(scores, anchors, topidx);
    crop_mean<<<6144, 256, 0, stream>>>(x, anchors, topidx, abar);

    part_gemm<<<dim3(32, 8), 256, 0, stream>>>(abar, bbwh, concat);
    cls_gemm<<<dim3(25, 32), 256, 0, stream>>>(concat, cn_w, out);
}